// Round 7
// baseline (50937.546 us; speedup 1.0000x reference)
//
#include <hip/hip_runtime.h>

typedef unsigned short u16;

#define SCALE_F 0.08838834764831845f

// VEC offsets (u16 elems) — small params
#define VC_PW    0
#define VC_PB    1408
#define VC_N1W   1536
#define VC_N1B   1792
#define VC_QKVB  2048
#define VC_PROJB 2816
#define VC_N2W   3072
#define VC_N2B   3328
#define VC_B1    3584
#define VC_B2    4608
#define VC_NFW   4864
#define VC_NFB   4992
#define VC_RPB   5120
#define VC_OW    6592
#define VC_OBIAS 44480

// WV offsets (u16 elems) — big weights, ORIGINAL [K][N] layout
#define WV_QKV  0
#define WV_PROJ 98304
#define WV_W1   131072
#define WV_W2   262144

__device__ __forceinline__ float bf2f(u16 x) {
  union { unsigned int i; float f; } v; v.i = ((unsigned int)x) << 16; return v.f;
}
__device__ __forceinline__ u16 f2bf(float f) {
  union { float f; unsigned int i; } v; v.f = f;
  unsigned int x = v.i;
  return (u16)((x + 0x7fffu + ((x >> 16) & 1u)) >> 16);
}
__device__ __forceinline__ unsigned int packbf(float a, float b) {
  return (unsigned int)f2bf(a) | ((unsigned int)f2bf(b) << 16);
}
__device__ __forceinline__ float wsum(float v) {
#pragma unroll
  for (int m = 32; m >= 1; m >>= 1) v += __shfl_xor(v, m, 64);
  return v;
}

// -------- dtype scan: count bf16-NaN patterns + zeros at even u16 indices --------
__global__ __launch_bounds__(256) void k_scan(const u16* __restrict__ raw, int* __restrict__ flag) {
  int nanc = 0, ez = 0;
  for (int i = threadIdx.x; i < 131072; i += 256) {
    u16 x = raw[i];
    if ((x & 0x7F80u) == 0x7F80u) nanc++;
    if (!(i & 1) && x == 0) ez++;
  }
  atomicAdd(&flag[1], nanc);
  atomicAdd(&flag[2], ez);
}
// decision: fp32 (true or bf16-in-fp32-container) => 1, bf16-packed => 0
__global__ void k_decide(int* __restrict__ flag) {
  if (threadIdx.x == 0) flag[0] = (flag[1] > 0 || flag[2] > 49152) ? 1 : 0;
}

// -------- dual-mode convert --------
__global__ __launch_bounds__(256) void k_conv(const void* __restrict__ src, u16* __restrict__ dst,
                                              int n, const int* __restrict__ flag) {
  const int fl = *flag;
  int i = blockIdx.x * 256 + threadIdx.x;
  if (i < n) {
    dst[i] = fl ? f2bf(((const float*)src)[i]) : ((const u16*)src)[i];
  }
}

// ---------------- patch embed ----------------
__global__ __launch_bounds__(256) void k_patch(const u16* __restrict__ obs,
                                               const u16* __restrict__ vec,
                                               u16* __restrict__ X) {
  __shared__ float vis[2][11];
  const int tid = threadIdx.x;
  const int half = tid >> 7;
  const int c = tid & 127;
  const int tok = blockIdx.x * 2 + half;
  const int b = tok / 12000, rr = tok % 12000;
  const int d = rr / 1200, h = (rr / 40) % 30, w2 = rr % 40;
  if (c < 11) {
    vis[half][c] = bf2f(obs[(size_t)b * 132020 + ((d * 11 + c) * 30 + h) * 40 + w2]);
  }
  __syncthreads();
  float acc = bf2f(vec[VC_PB + c]);
#pragma unroll
  for (int ch = 0; ch < 11; ch++) acc += vis[half][ch] * bf2f(vec[VC_PW + ch * 128 + c]);
  X[(size_t)tok * 128 + c] = f2bf(acc);
}

// ---------------- LN1 + roll + window-gather ----------------
__global__ __launch_bounds__(256) void k_ln_gather(const u16* __restrict__ X, u16* __restrict__ Yc,
                                                   const u16* __restrict__ nw,
                                                   const u16* __restrict__ nb,
                                                   int shift, int row_base) {
  const int tid = threadIdx.x, lane = tid & 63, wv = tid >> 6;
  const int rowl = blockIdx.x * 4 + wv;
  const int rowg = row_base + rowl;
  const int win = rowg / 125, n = rowg % 125;
  const int b = win / 96, wb = win % 96;
  const int wd = wb / 48, wh = (wb / 8) % 6, ww = wb % 8;
  const int ld = n / 25, lh = (n / 5) % 5, lw = n % 5;
  int d = wd * 5 + ld + shift; if (d >= 10) d -= 10;
  int h = wh * 5 + lh + shift; if (h >= 30) h -= 30;
  int w = ww * 5 + lw + shift; if (w >= 40) w -= 40;
  const u16* xp = X + ((((size_t)b * 10 + d) * 30 + h) * 40 + w) * 128;
  unsigned int u = *(const unsigned int*)(xp + 2 * lane);
  float x0 = bf2f((u16)(u & 0xffff)), x1 = bf2f((u16)(u >> 16));
  float mean = wsum(x0 + x1) * (1.f / 128.f);
  float var = wsum(x0 * x0 + x1 * x1) * (1.f / 128.f) - mean * mean;
  float rstd = rsqrtf(var + 1e-5f);
  float y0 = (x0 - mean) * rstd * bf2f(nw[2 * lane]) + bf2f(nb[2 * lane]);
  float y1 = (x1 - mean) * rstd * bf2f(nw[2 * lane + 1]) + bf2f(nb[2 * lane + 1]);
  *(unsigned int*)(Yc + (size_t)rowl * 128 + 2 * lane) = packbf(y0, y1);
}

// ---------------- plain LN (natural token order) ----------------
__global__ __launch_bounds__(256) void k_ln_plain(const u16* __restrict__ X, u16* __restrict__ Yt,
                                                  const u16* __restrict__ nw,
                                                  const u16* __restrict__ nb, int t0) {
  const int tid = threadIdx.x, lane = tid & 63, wv = tid >> 6;
  const int rowl = blockIdx.x * 4 + wv;
  const u16* xp = X + (size_t)(t0 + rowl) * 128;
  unsigned int u = *(const unsigned int*)(xp + 2 * lane);
  float x0 = bf2f((u16)(u & 0xffff)), x1 = bf2f((u16)(u >> 16));
  float mean = wsum(x0 + x1) * (1.f / 128.f);
  float var = wsum(x0 * x0 + x1 * x1) * (1.f / 128.f) - mean * mean;
  float rstd = rsqrtf(var + 1e-5f);
  float y0 = (x0 - mean) * rstd * bf2f(nw[2 * lane]) + bf2f(nb[2 * lane]);
  float y1 = (x1 - mean) * rstd * bf2f(nw[2 * lane + 1]) + bf2f(nb[2 * lane + 1]);
  *(unsigned int*)(Yt + (size_t)rowl * 128 + 2 * lane) = packbf(y0, y1);
}

// ---------------- naive GEMM: C[M,N] = A[M,K] @ W[K,N] + bias ----------------
__global__ __launch_bounds__(256) void k_gemm_naive(const u16* __restrict__ A,
                                                    const u16* __restrict__ W,
                                                    const u16* __restrict__ bias,
                                                    u16* __restrict__ C,
                                                    int M, int N, int K, int mode) {
  const int id = blockIdx.x * 256 + threadIdx.x;
  if (id >= M * N) return;
  const int row = id / N, col = id % N;
  float acc = bf2f(bias[col]);
  const u16* a = A + (size_t)row * K;
  const u16* w = W + col;
  for (int k = 0; k < K; k++) acc += bf2f(a[k]) * bf2f(w[(size_t)k * N]);
  if (mode == 1 && col < 128) acc *= SCALE_F;
  if (mode == 2) acc = 0.5f * acc * (1.f + erff(acc * 0.70710678118654752f));
  C[(size_t)id] = f2bf(acc);
}

// ---------------- naive windowed attention: one block(128) per (window, query) ----------------
__global__ __launch_bounds__(128) void k_attn_naive(const u16* __restrict__ QKVc,
                                                    u16* __restrict__ OBc,
                                                    const u16* __restrict__ rpb,
                                                    int win_base, int boundary) {
  __shared__ float sS[125];
  __shared__ float sP[125];
  const int widl = blockIdx.x / 125;
  const int q = blockIdx.x % 125;
  const int wing = win_base + widl;
  const int wb = wing % 96;
  const int wd = wb / 48, wh = (wb / 8) % 6, ww = wb % 8;
  const int ldq = q / 25, lhq = (q / 5) % 5, lwq = q % 5;
  const u16* B = QKVc + (size_t)widl * (125 * 384);
  const int j = threadIdx.x;
  if (j < 125) {
    const int ldk = j / 25, lhk = (j / 5) % 5, lwk = j % 5;
    float s = 0.f;
    for (int c = 0; c < 128; c++)
      s += bf2f(B[q * 384 + c]) * bf2f(B[j * 384 + 128 + c]);
    s += bf2f(rpb[((ldq - ldk + 4) * 9 + (lhq - lhk + 4)) * 9 + (lwq - lwk + 4)]);
    if (ldq < ldk) s -= 100.f;
    if (boundary) {
      int ghq = wh * 5 + lhq, gwq = ww * 5 + lwq, gdq = wd * 5 + ldq;
      int ghk = wh * 5 + lhk, gwk = ww * 5 + lwk, gdk = wd * 5 + ldk;
      int regQ = (gdq < 5 ? 0 : (gdq < 8 ? 1 : 2)) * 9 +
                 (ghq < 25 ? 0 : (ghq < 28 ? 1 : 2)) * 3 +
                 (gwq < 35 ? 0 : (gwq < 38 ? 1 : 2));
      int regK = (gdk < 5 ? 0 : (gdk < 8 ? 1 : 2)) * 9 +
                 (ghk < 25 ? 0 : (ghk < 28 ? 1 : 2)) * 3 +
                 (gwk < 35 ? 0 : (gwk < 38 ? 1 : 2));
      if (regQ != regK) s -= 100.f;
    }
    sS[j] = s;
  }
  __syncthreads();
  float mx = -1e30f;
  for (int jj = 0; jj < 125; jj++) mx = fmaxf(mx, sS[jj]);
  float sm = 0.f;
  for (int jj = 0; jj < 125; jj++) sm += __expf(sS[jj] - mx);
  __syncthreads();
  if (j < 125) sP[j] = __expf(sS[j] - mx) / sm;
  __syncthreads();
  float o = 0.f;
  for (int jj = 0; jj < 125; jj++)
    o += sP[jj] * bf2f(B[jj * 384 + 256 + threadIdx.x]);
  OBc[((size_t)widl * 125 + q) * 128 + threadIdx.x] = f2bf(o);
}

// ---------------- naive proj + window-reverse + roll-back + residual add ----------------
__global__ __launch_bounds__(256) void k_proj_scatter(const u16* __restrict__ OBc,
                                                      const u16* __restrict__ W,
                                                      const u16* __restrict__ bias,
                                                      u16* __restrict__ X,
                                                      int shift, int win_base, int nrows) {
  const int id = blockIdx.x * 256 + threadIdx.x;
  if (id >= nrows * 128) return;
  const int row = id >> 7, col = id & 127;
  float acc = bf2f(bias[col]);
  const u16* a = OBc + (size_t)row * 128;
  for (int k = 0; k < 128; k++) acc += bf2f(a[k]) * bf2f(W[k * 128 + col]);
  const int wing = win_base + row / 125, n = row % 125;
  const int b = wing / 96, wb = wing % 96;
  const int wd = wb / 48, wh = (wb / 8) % 6, ww = wb % 8;
  const int ld = n / 25, lh = (n / 5) % 5, lw = n % 5;
  int d = wd * 5 + ld + shift; if (d >= 10) d -= 10;
  int h = wh * 5 + lh + shift; if (h >= 30) h -= 30;
  int w = ww * 5 + lw + shift; if (w >= 40) w -= 40;
  const size_t xi = ((((size_t)b * 10 + d) * 30 + h) * 40 + w) * 128 + col;
  X[xi] = f2bf(bf2f(X[xi]) + acc);
}

// ---------------- naive fc2 + residual add ----------------
__global__ __launch_bounds__(256) void k_fc2_add(const u16* __restrict__ Hc,
                                                 const u16* __restrict__ W,
                                                 const u16* __restrict__ bias,
                                                 u16* __restrict__ X, int t0, int nrows) {
  const int id = blockIdx.x * 256 + threadIdx.x;
  if (id >= nrows * 128) return;
  const int row = id >> 7, col = id & 127;
  float acc = bf2f(bias[col]);
  const u16* a = Hc + (size_t)row * 512;
  for (int k = 0; k < 512; k++) acc += bf2f(a[k]) * bf2f(W[k * 128 + col]);
  const size_t xi = (size_t)(t0 + row) * 128 + col;
  X[xi] = f2bf(bf2f(X[xi]) + acc);
}

// ---------------- final LN + partial pooling ----------------
__global__ __launch_bounds__(256) void k_pool(const u16* __restrict__ X, const u16* __restrict__ vec,
                                              float* __restrict__ pool) {
  __shared__ float sacc[4][128];
  const int tid = threadIdx.x, lane = tid & 63, wv = tid >> 6;
  const int b = blockIdx.x / 10, slice = blockIdx.x % 10;
  const float nw0 = bf2f(vec[VC_NFW + 2 * lane]), nb0 = bf2f(vec[VC_NFB + 2 * lane]);
  const float nw1 = bf2f(vec[VC_NFW + 2 * lane + 1]), nb1 = bf2f(vec[VC_NFB + 2 * lane + 1]);
  float a0 = 0.f, a1 = 0.f;
  for (int t = wv; t < 1200; t += 4) {
    size_t token = (size_t)b * 12000 + slice * 1200 + t;
    unsigned int u = *(const unsigned int*)(X + token * 128 + 2 * lane);
    float x0 = bf2f((u16)(u & 0xffff)), x1 = bf2f((u16)(u >> 16));
    float mean = wsum(x0 + x1) * (1.f / 128.f);
    float var = wsum(x0 * x0 + x1 * x1) * (1.f / 128.f) - mean * mean;
    float rstd = rsqrtf(var + 1e-5f);
    a0 += (x0 - mean) * rstd * nw0 + nb0;
    a1 += (x1 - mean) * rstd * nw1 + nb1;
  }
  sacc[wv][2 * lane] = a0;
  sacc[wv][2 * lane + 1] = a1;
  __syncthreads();
  if (tid < 128) {
    float s = sacc[0][tid] + sacc[1][tid] + sacc[2][tid] + sacc[3][tid];
    atomicAdd(pool + b * 128 + tid, s);
  }
}

// ---------------- head: OUTPUT IS FLOAT32 (reference returns jnp.float32) ----------------
__global__ __launch_bounds__(256) void k_head(const float* __restrict__ pool,
                                              const u16* __restrict__ obs,
                                              const u16* __restrict__ vec,
                                              float* __restrict__ out) {
  const int b = blockIdx.x, o = threadIdx.x;
  float acc = bf2f(vec[VC_OBIAS + o]);
  for (int i = 0; i < 128; i++)
    acc += pool[b * 128 + i] * (1.f / 12000.f) * bf2f(vec[VC_OW + i * 256 + o]);
  for (int i = 0; i < 20; i++)
    acc += bf2f(obs[(size_t)b * 132020 + 132000 + i]) * bf2f(vec[VC_OW + (128 + i) * 256 + o]);
  out[b * 256 + o] = acc;
}

extern "C" void kernel_launch(void* const* d_in, const int* in_sizes, int n_in,
                              void* d_out, int out_size, void* d_ws, size_t ws_size,
                              hipStream_t stream) {
  // ---- adaptive layout: CRITICAL small buffers FIRST, chunk buffers last ----
  u16* base  = (u16*)d_ws;
  int* flag  = (int*)d_ws;
  float* pool = (float*)((char*)d_ws + 16);
  u16* VEC   = base + 10000;           //     45,056
  u16* WV    = VEC + 45056;            //    393,216
  u16* OBSC  = WV + 393216;            //  4,224,640
  u16* X     = OBSC + 4224640;         // 49,152,000
  u16* Yc    = X + 49152000;           // CW*16,000
  const long long cap = (long long)(ws_size / 2);
  const long long fixed = 10000 + 45056 + 393216 + 4224640 + 49152000;
  int CW = 48, TM = 4000;
  if (fixed + 384LL * 80000 <= cap)      { CW = 384; TM = 32000; }
  else if (fixed + 192LL * 80000 <= cap) { CW = 192; TM = 16000; }
  else if (fixed + 96LL * 80000 <= cap)  { CW = 96;  TM = 8000;  }
  u16* QKVc = Yc + (size_t)CW * 16000;   // CW*48,000 (aliases Hc)
  u16* OBc  = QKVc + (size_t)CW * 48000; // CW*16,000

  hipMemsetAsync(d_ws, 0, 16 + 32 * 128 * sizeof(float), stream);
  k_scan<<<1, 256, 0, stream>>>((const u16*)d_in[0], flag);
  k_decide<<<1, 64, 0, stream>>>(flag);

  // converts: small params
  struct CV { int idx; int off; int n; };
  const CV cvs[] = {
      {1, VC_PW, 1408},  {2, VC_PB, 128},   {3, VC_N1W, 256},  {4, VC_N1B, 256},
      {6, VC_QKVB, 768}, {9, VC_PROJB, 256},{10, VC_N2W, 256}, {11, VC_N2B, 256},
      {13, VC_B1, 1024}, {15, VC_B2, 256},  {16, VC_NFW, 128}, {17, VC_NFB, 128},
      {7, VC_RPB, 1458}, {18, VC_OW, 37888},{19, VC_OBIAS, 256}};
  for (const auto& c : cvs)
    k_conv<<<(c.n + 255) / 256, 256, 0, stream>>>(d_in[c.idx], VEC + c.off, c.n, flag);
  k_conv<<<16504, 256, 0, stream>>>(d_in[0], OBSC, 4224640, flag);
  // converts: big weights, original [K][N] layout
  k_conv<<<384, 256, 0, stream>>>(d_in[5],  WV + WV_QKV,  98304,  flag);
  k_conv<<<128, 256, 0, stream>>>(d_in[8],  WV + WV_PROJ, 32768,  flag);
  k_conv<<<512, 256, 0, stream>>>(d_in[12], WV + WV_W1,   131072, flag);
  k_conv<<<512, 256, 0, stream>>>(d_in[14], WV + WV_W2,   131072, flag);

  k_patch<<<192000, 256, 0, stream>>>(OBSC, VEC, X);

  const int CR = CW * 125;  // rows per attention chunk
  for (int l = 0; l < 2; l++) {
    const int shift = l ? 2 : 0;
    for (int wb0 = 0; wb0 < 3072; wb0 += CW) {
      k_ln_gather<<<CR / 4, 256, 0, stream>>>(X, Yc, VEC + VC_N1W + l * 128,
                                              VEC + VC_N1B + l * 128, shift, wb0 * 125);
      k_gemm_naive<<<(CR * 384) / 256, 256, 0, stream>>>(Yc, WV + WV_QKV + l * 49152,
                                                         VEC + VC_QKVB + l * 384, QKVc,
                                                         CR, 384, 128, 1);
      k_attn_naive<<<CR, 128, 0, stream>>>(QKVc, OBc, VEC + VC_RPB + l * 729, wb0, l);
      k_proj_scatter<<<(CR * 128) / 256, 256, 0, stream>>>(OBc, WV + WV_PROJ + l * 16384,
                                                           VEC + VC_PROJB + l * 128, X,
                                                           shift, wb0, CR);
    }
    for (int t0 = 0; t0 < 384000; t0 += TM) {
      k_ln_plain<<<TM / 4, 256, 0, stream>>>(X, Yc, VEC + VC_N2W + l * 128,
                                             VEC + VC_N2B + l * 128, t0);
      k_gemm_naive<<<(TM * 512) / 256, 256, 0, stream>>>(Yc, WV + WV_W1 + l * 65536,
                                                         VEC + VC_B1 + l * 512, QKVc,
                                                         TM, 512, 128, 2);
      k_fc2_add<<<(TM * 128) / 256, 256, 0, stream>>>(QKVc, WV + WV_W2 + l * 65536,
                                                      VEC + VC_B2 + l * 128, X, t0, TM);
    }
  }

  k_pool<<<320, 256, 0, stream>>>(X, VEC, pool);
  k_head<<<32, 256, 0, stream>>>(pool, OBSC, VEC, (float*)d_out);
}

// Round 8
// 4403.855 us; speedup vs baseline: 11.5666x; 11.5666x over previous
//
#include <hip/hip_runtime.h>

typedef unsigned short u16;
typedef short bf16x8 __attribute__((ext_vector_type(8)));
typedef float f32x4 __attribute__((ext_vector_type(4)));

#define SCALE_F 0.08838834764831845f
#define LDA 136

// VEC offsets (u16 elems)
#define VC_PW    0
#define VC_PB    1408
#define VC_N1W   1536
#define VC_N1B   1792
#define VC_QKVB  2048
#define VC_PROJB 2816
#define VC_N2W   3072
#define VC_N2B   3328
#define VC_B1    3584
#define VC_B2    4608
#define VC_NFW   4864
#define VC_NFB   4992
#define VC_RPB   5120
#define VC_OW    6592
#define VC_OBIAS 44480

// WT offsets (u16 elems) — transposed weights [N][K]
#define WT_QKV  0
#define WT_PROJ 98304
#define WT_W1   131072
#define WT_W2   262144

__device__ __forceinline__ float bf2f(u16 x) {
  union { unsigned int i; float f; } v; v.i = ((unsigned int)x) << 16; return v.f;
}
__device__ __forceinline__ u16 f2bf(float f) {
  union { float f; unsigned int i; } v; v.f = f;
  unsigned int x = v.i;
  return (u16)((x + 0x7fffu + ((x >> 16) & 1u)) >> 16);
}
__device__ __forceinline__ unsigned int packbf(float a, float b) {
  return (unsigned int)f2bf(a) | ((unsigned int)f2bf(b) << 16);
}
__device__ __forceinline__ float wsum(float v) {
#pragma unroll
  for (int m = 32; m >= 1; m >>= 1) v += __shfl_xor(v, m, 64);
  return v;
}
__device__ __forceinline__ float wmax(float v) {
#pragma unroll
  for (int m = 32; m >= 1; m >>= 1) v = fmaxf(v, __shfl_xor(v, m, 64));
  return v;
}

// -------- dtype scan + decide (fp32 containers vs bf16-packed) --------
__global__ __launch_bounds__(256) void k_scan(const u16* __restrict__ raw, int* __restrict__ flag) {
  int nanc = 0, ez = 0;
  for (int i = threadIdx.x; i < 131072; i += 256) {
    u16 x = raw[i];
    if ((x & 0x7F80u) == 0x7F80u) nanc++;
    if (!(i & 1) && x == 0) ez++;
  }
  atomicAdd(&flag[1], nanc);
  atomicAdd(&flag[2], ez);
}
__global__ void k_decide(int* __restrict__ flag) {
  if (threadIdx.x == 0) flag[0] = (flag[1] > 0 || flag[2] > 49152) ? 1 : 0;
}

// -------- dual-mode converts --------
__global__ __launch_bounds__(256) void k_conv(const void* __restrict__ src, u16* __restrict__ dst,
                                              int n, const int* __restrict__ flag) {
  const int fl = *flag;
  int i = blockIdx.x * 256 + threadIdx.x;
  if (i < n) dst[i] = fl ? f2bf(((const float*)src)[i]) : ((const u16*)src)[i];
}
__global__ __launch_bounds__(256) void k_convT2(const void* __restrict__ src, u16* __restrict__ dst,
                                                int K, int N, int eoff, const int* __restrict__ flag) {
  const int fl = *flag;
  int id = blockIdx.x * 256 + threadIdx.x;
  if (id < K * N) {
    int n = id / K, k = id % K;
    dst[id] = fl ? f2bf(((const float*)src)[eoff + k * N + n])
                 : ((const u16*)src)[eoff + k * N + n];
  }
}

// ---------------- patch embed ----------------
__global__ __launch_bounds__(256) void k_patch(const u16* __restrict__ obs,
                                               const u16* __restrict__ vec,
                                               u16* __restrict__ X) {
  __shared__ float vis[2][11];
  const int tid = threadIdx.x;
  const int half = tid >> 7;
  const int c = tid & 127;
  const int tok = blockIdx.x * 2 + half;
  const int b = tok / 12000, rr = tok % 12000;
  const int d = rr / 1200, h = (rr / 40) % 30, w2 = rr % 40;
  if (c < 11) {
    vis[half][c] = bf2f(obs[(size_t)b * 132020 + ((d * 11 + c) * 30 + h) * 40 + w2]);
  }
  __syncthreads();
  float acc = bf2f(vec[VC_PB + c]);
#pragma unroll
  for (int ch = 0; ch < 11; ch++) acc += vis[half][ch] * bf2f(vec[VC_PW + ch * 128 + c]);
  X[(size_t)tok * 128 + c] = f2bf(acc);
}

// ---------------- MFMA GEMM: fused LN1+roll+window-gather -> QKV chunk ----------------
__global__ __launch_bounds__(256) void k_gemm_qkv(const u16* __restrict__ X,
                                                  const u16* __restrict__ WTp,
                                                  const u16* __restrict__ bias,
                                                  const u16* __restrict__ nw,
                                                  const u16* __restrict__ nb,
                                                  u16* __restrict__ Out, int shift,
                                                  int row_base) {
  __shared__ u16 sA[64 * LDA];
  __shared__ u16 sB[64 * LDA];
  const int tid = threadIdx.x, lane = tid & 63, wv = tid >> 6;
  const int mbase = blockIdx.x * 64;
  const float nw0 = bf2f(nw[2 * lane]), nb0 = bf2f(nb[2 * lane]);
  const float nw1 = bf2f(nw[2 * lane + 1]), nb1 = bf2f(nb[2 * lane + 1]);
  for (int r = 0; r < 16; r++) {
    int row = wv * 16 + r;
    int rowg = row_base + mbase + row;
    int win = rowg / 125, n = rowg % 125;
    int b = win / 96, winb = win % 96;
    int wd = winb / 48, wh = (winb >> 3) % 6, ww = winb & 7;
    int ld = n / 25, lh = (n / 5) % 5, lw = n % 5;
    int d = wd * 5 + ld + shift; if (d >= 10) d -= 10;
    int h = wh * 5 + lh + shift; if (h >= 30) h -= 30;
    int w2 = ww * 5 + lw + shift; if (w2 >= 40) w2 -= 40;
    const u16* xp = X + ((((size_t)b * 10 + d) * 30 + h) * 40 + w2) * 128;
    unsigned int u = *(const unsigned int*)(xp + 2 * lane);
    float x0 = bf2f((u16)(u & 0xffff)), x1 = bf2f((u16)(u >> 16));
    float mean = wsum(x0 + x1) * (1.f / 128.f);
    float var = wsum(x0 * x0 + x1 * x1) * (1.f / 128.f) - mean * mean;
    float rstd = rsqrtf(var + 1e-5f);
    float y0 = (x0 - mean) * rstd * nw0 + nb0;
    float y1 = (x1 - mean) * rstd * nw1 + nb1;
    *(unsigned int*)(sA + row * LDA + 2 * lane) = packbf(y0, y1);
  }
  const int m = lane & 15, quad = lane >> 4;
  for (int nc = 0; nc < 6; nc++) {
    __syncthreads();
#pragma unroll
    for (int i = 0; i < 4; i++) {
      int idx = tid + i * 256;
      int row = idx >> 4, c16 = idx & 15;
      *(uint4*)(sB + row * LDA + c16 * 8) =
          *(const uint4*)(WTp + (size_t)(nc * 64 + row) * 128 + c16 * 8);
    }
    __syncthreads();
    f32x4 acc[4];
#pragma unroll
    for (int nt = 0; nt < 4; nt++)
#pragma unroll
      for (int r = 0; r < 4; r++) acc[nt][r] = 0.f;
#pragma unroll
    for (int kc = 0; kc < 4; kc++) {
      bf16x8 a = *(const bf16x8*)(sA + (wv * 16 + m) * LDA + kc * 32 + quad * 8);
#pragma unroll
      for (int nt = 0; nt < 4; nt++) {
        bf16x8 bb = *(const bf16x8*)(sB + (nt * 16 + m) * LDA + kc * 32 + quad * 8);
        acc[nt] = __builtin_amdgcn_mfma_f32_16x16x32_bf16(a, bb, acc[nt], 0, 0, 0);
      }
    }
#pragma unroll
    for (int nt = 0; nt < 4; nt++) {
      int col = nc * 64 + nt * 16 + m;
      float bv = bf2f(bias[col]);
      float scl = (col < 128) ? SCALE_F : 1.f;
#pragma unroll
      for (int r = 0; r < 4; r++) {
        int row = mbase + wv * 16 + quad * 4 + r;
        Out[(size_t)row * 384 + col] = f2bf((acc[nt][r] + bv) * scl);
      }
    }
  }
}

// ---------------- MFMA GEMM: proj (reads OB) + roll-back + residual scatter-add ----------------
__global__ __launch_bounds__(256) void k_gemm_proj(const u16* __restrict__ In,
                                                   const u16* __restrict__ WTp,
                                                   const u16* __restrict__ bias,
                                                   u16* __restrict__ X, int shift,
                                                   int win_base) {
  __shared__ u16 sA[64 * LDA];
  __shared__ u16 sB[64 * LDA];
  const int tid = threadIdx.x;
  const int mbase = blockIdx.x * 64;
#pragma unroll
  for (int i = 0; i < 4; i++) {
    int idx = tid + i * 256;
    int row = idx >> 4, c16 = idx & 15;
    *(uint4*)(sA + row * LDA + c16 * 8) =
        *(const uint4*)(In + (size_t)(mbase + row) * 128 + c16 * 8);
  }
  const int lane = tid & 63, wv = tid >> 6;
  const int m = lane & 15, quad = lane >> 4;
  size_t xbase[4];
#pragma unroll
  for (int r = 0; r < 4; r++) {
    int rowl = mbase + wv * 16 + quad * 4 + r;
    int win = win_base + rowl / 125, n = rowl % 125;
    int b = win / 96, winb = win % 96;
    int wd = winb / 48, wh = (winb >> 3) % 6, ww = winb & 7;
    int ld = n / 25, lh = (n / 5) % 5, lw = n % 5;
    int d = wd * 5 + ld + shift; if (d >= 10) d -= 10;
    int h = wh * 5 + lh + shift; if (h >= 30) h -= 30;
    int w2 = ww * 5 + lw + shift; if (w2 >= 40) w2 -= 40;
    xbase[r] = ((((size_t)b * 10 + d) * 30 + h) * 40 + w2) * 128;
  }
  for (int nc = 0; nc < 2; nc++) {
    __syncthreads();
#pragma unroll
    for (int i = 0; i < 4; i++) {
      int idx = tid + i * 256;
      int row = idx >> 4, c16 = idx & 15;
      *(uint4*)(sB + row * LDA + c16 * 8) =
          *(const uint4*)(WTp + (size_t)(nc * 64 + row) * 128 + c16 * 8);
    }
    __syncthreads();
    f32x4 acc[4];
#pragma unroll
    for (int nt = 0; nt < 4; nt++)
#pragma unroll
      for (int r = 0; r < 4; r++) acc[nt][r] = 0.f;
#pragma unroll
    for (int kc = 0; kc < 4; kc++) {
      bf16x8 a = *(const bf16x8*)(sA + (wv * 16 + m) * LDA + kc * 32 + quad * 8);
#pragma unroll
      for (int nt = 0; nt < 4; nt++) {
        bf16x8 bb = *(const bf16x8*)(sB + (nt * 16 + m) * LDA + kc * 32 + quad * 8);
        acc[nt] = __builtin_amdgcn_mfma_f32_16x16x32_bf16(a, bb, acc[nt], 0, 0, 0);
      }
    }
#pragma unroll
    for (int nt = 0; nt < 4; nt++) {
      int col = nc * 64 + nt * 16 + m;
      float bv = bf2f(bias[col]);
#pragma unroll
      for (int r = 0; r < 4; r++) {
        size_t xi = xbase[r] + col;
        X[xi] = f2bf(bf2f(X[xi]) + acc[nt][r] + bv);
      }
    }
  }
}

// ---------------- windowed attention core (VALU, XOR-swizzled LDS): QKV -> OB ----------------
__global__ __launch_bounds__(256) void k_attn(const u16* __restrict__ QKV, u16* __restrict__ OB,
                                              const u16* __restrict__ rpb, int win_base,
                                              int boundary) {
  __shared__ u16 sK[125 * 128];
  __shared__ u16 sV[125 * 128];
  const int tid = threadIdx.x, lane = tid & 63, wv = tid >> 6;
  const int winl = blockIdx.x;
  const int wing = win_base + winl;
  const int winb = wing % 96;
  const int wd = winb / 48, wh = (winb >> 3) % 6, ww = winb & 7;
  const u16* base = QKV + (size_t)winl * (125 * 384);
  for (int idx = tid; idx < 125 * 32; idx += 256) {
    int j = idx >> 5, g = idx & 31;
    const u16* src = base + j * 384 + (g << 2);
    uint2 kv = *(const uint2*)(src + 128);
    uint2 vvv = *(const uint2*)(src + 256);
    int phys = j * 128 + ((((g >> 1) ^ (j & 7))) << 3) + ((g & 1) << 2);
    *(uint2*)(sK + phys) = kv;
    *(uint2*)(sV + phys) = vvv;
  }
  __syncthreads();
  const int jA = lane;
  const int jB = lane + 64;
  const bool vB = jB < 125;
  const int jBc = vB ? jB : 124;
  const int ldA = jA / 25, lhA = (jA / 5) % 5, lwA = jA % 5;
  const int ldB = jBc / 25, lhB = (jBc / 5) % 5, lwB = jBc % 5;
  int regA = 0, regB = 0;
  if (boundary) {
    int gd = wd * 5 + ldA, gh = wh * 5 + lhA, gw = ww * 5 + lwA;
    regA = (gd < 5 ? 0 : (gd < 8 ? 1 : 2)) * 9 + (gh < 25 ? 0 : (gh < 28 ? 1 : 2)) * 3 +
           (gw < 35 ? 0 : (gw < 38 ? 1 : 2));
    gd = wd * 5 + ldB; gh = wh * 5 + lhB; gw = ww * 5 + lwB;
    regB = (gd < 5 ? 0 : (gd < 8 ? 1 : 2)) * 9 + (gh < 25 ? 0 : (gh < 28 ? 1 : 2)) * 3 +
           (gw < 35 ? 0 : (gw < 38 ? 1 : 2));
  }
  const int vswz_off = ((2 * lane) & 7);
  for (int g = 0; g < 8; g++) {
    const int q0 = wv * 4 + g * 16;
    float s0[4] = {0.f, 0.f, 0.f, 0.f}, s1[4] = {0.f, 0.f, 0.f, 0.f};
    for (int c0 = 0; c0 < 128; c0 += 8) {
      float qf[4][8];
#pragma unroll
      for (int i = 0; i < 4; i++) {
        int qi = q0 + i; if (qi > 124) qi = 124;
        uint4 qv = *(const uint4*)(base + qi * 384 + c0);
        qf[i][0] = bf2f((u16)(qv.x & 0xffff)); qf[i][1] = bf2f((u16)(qv.x >> 16));
        qf[i][2] = bf2f((u16)(qv.y & 0xffff)); qf[i][3] = bf2f((u16)(qv.y >> 16));
        qf[i][4] = bf2f((u16)(qv.z & 0xffff)); qf[i][5] = bf2f((u16)(qv.z >> 16));
        qf[i][6] = bf2f((u16)(qv.w & 0xffff)); qf[i][7] = bf2f((u16)(qv.w >> 16));
      }
      bf16x8 ka = *(const bf16x8*)(sK + jA * 128 + ((((c0 >> 3) ^ (jA & 7))) << 3));
      bf16x8 kb = *(const bf16x8*)(sK + jBc * 128 + ((((c0 >> 3) ^ (jBc & 7))) << 3));
      float kaf[8], kbf[8];
#pragma unroll
      for (int e = 0; e < 8; e++) { kaf[e] = bf2f((u16)ka[e]); kbf[e] = bf2f((u16)kb[e]); }
#pragma unroll
      for (int i = 0; i < 4; i++) {
#pragma unroll
        for (int e = 0; e < 8; e++) {
          s0[i] += qf[i][e] * kaf[e];
          s1[i] += qf[i][e] * kbf[e];
        }
      }
    }
    float pA[4], pB[4];
#pragma unroll
    for (int i = 0; i < 4; i++) {
      int qi = q0 + i; int qic = qi > 124 ? 124 : qi;
      int ldq = qic / 25, lhq = (qic / 5) % 5, lwq = qic % 5;
      int idxA = ((ldq - ldA + 4) * 9 + (lhq - lhA + 4)) * 9 + (lwq - lwA + 4);
      int idxB = ((ldq - ldB + 4) * 9 + (lhq - lhB + 4)) * 9 + (lwq - lwB + 4);
      float a = s0[i] + bf2f(rpb[idxA]);
      float bq = s1[i] + bf2f(rpb[idxB]);
      if (ldq < ldA) a -= 100.f;
      if (ldq < ldB) bq -= 100.f;
      if (boundary) {
        int gd = wd * 5 + ldq, gh = wh * 5 + lhq, gw = ww * 5 + lwq;
        int regQ = (gd < 5 ? 0 : (gd < 8 ? 1 : 2)) * 9 +
                   (gh < 25 ? 0 : (gh < 28 ? 1 : 2)) * 3 + (gw < 35 ? 0 : (gw < 38 ? 1 : 2));
        if (regQ != regA) a -= 100.f;
        if (regQ != regB) bq -= 100.f;
      }
      if (!vB) bq = -1e30f;
      float mx = wmax(fmaxf(a, bq));
      float ea = __expf(a - mx);
      float eb = vB ? __expf(bq - mx) : 0.f;
      float sm = wsum(ea + eb);
      float inv = 1.f / sm;
      pA[i] = ea * inv; pB[i] = eb * inv;
    }
    float oa[4] = {0.f, 0.f, 0.f, 0.f}, ob[4] = {0.f, 0.f, 0.f, 0.f};
    for (int j = 0; j < 64; j++) {
      unsigned int u =
          *(const unsigned int*)(sV + j * 128 + ((((lane >> 2) ^ (j & 7))) << 3) + vswz_off);
      float v0 = bf2f((u16)(u & 0xffff)), v1 = bf2f((u16)(u >> 16));
#pragma unroll
      for (int i = 0; i < 4; i++) {
        float pj = __shfl(pA[i], j, 64);
        oa[i] += pj * v0; ob[i] += pj * v1;
      }
    }
    for (int j = 64; j < 125; j++) {
      unsigned int u =
          *(const unsigned int*)(sV + j * 128 + ((((lane >> 2) ^ (j & 7))) << 3) + vswz_off);
      float v0 = bf2f((u16)(u & 0xffff)), v1 = bf2f((u16)(u >> 16));
#pragma unroll
      for (int i = 0; i < 4; i++) {
        float pj = __shfl(pB[i], j - 64, 64);
        oa[i] += pj * v0; ob[i] += pj * v1;
      }
    }
#pragma unroll
    for (int i = 0; i < 4; i++) {
      int qi = q0 + i;
      if (qi < 125) {
        *(unsigned int*)(OB + ((size_t)winl * 125 + qi) * 128 + 2 * lane) = packbf(oa[i], ob[i]);
      }
    }
  }
}

// ---------------- fused LN2 + MLP + residual (in-place on X) ----------------
__global__ __launch_bounds__(256) void k_mlp(u16* __restrict__ X, const u16* __restrict__ W1T,
                                             const u16* __restrict__ b1, const u16* __restrict__ W2T,
                                             const u16* __restrict__ b2, const u16* __restrict__ nw,
                                             const u16* __restrict__ nb) {
  __shared__ u16 sIn[64 * LDA];
  __shared__ u16 sW1[64 * LDA];
  __shared__ u16 sH[64 * 72];
  __shared__ u16 sW2[128 * 72];
  const int tid = threadIdx.x, lane = tid & 63, wv = tid >> 6;
  const int m = lane & 15, quad = lane >> 4;
  const int mbase = blockIdx.x * 64;
  const float nw0 = bf2f(nw[2 * lane]), nb0 = bf2f(nb[2 * lane]);
  const float nw1 = bf2f(nw[2 * lane + 1]), nb1 = bf2f(nb[2 * lane + 1]);
  for (int r = 0; r < 16; r++) {
    int row = wv * 16 + r;
    unsigned int u = *(const unsigned int*)(X + (size_t)(mbase + row) * 128 + 2 * lane);
    float x0 = bf2f((u16)(u & 0xffff)), x1 = bf2f((u16)(u >> 16));
    float mean = wsum(x0 + x1) * (1.f / 128.f);
    float var = wsum(x0 * x0 + x1 * x1) * (1.f / 128.f) - mean * mean;
    float rstd = rsqrtf(var + 1e-5f);
    float y0 = (x0 - mean) * rstd * nw0 + nb0;
    float y1 = (x1 - mean) * rstd * nw1 + nb1;
    *(unsigned int*)(sIn + row * LDA + 2 * lane) = packbf(y0, y1);
  }
  f32x4 acc2[8];
#pragma unroll
  for (int nt = 0; nt < 8; nt++)
#pragma unroll
    for (int r = 0; r < 4; r++) acc2[nt][r] = 0.f;
  for (int hc = 0; hc < 8; hc++) {
    __syncthreads();
#pragma unroll
    for (int i = 0; i < 4; i++) {
      int idx = tid + i * 256;
      int row = idx >> 4, c16 = idx & 15;
      *(uint4*)(sW1 + row * LDA + c16 * 8) =
          *(const uint4*)(W1T + (size_t)(hc * 64 + row) * 128 + c16 * 8);
    }
#pragma unroll
    for (int i = 0; i < 4; i++) {
      int idx = tid + i * 256;
      int n = idx >> 3, c8 = idx & 7;
      *(uint4*)(sW2 + n * 72 + c8 * 8) = *(const uint4*)(W2T + (size_t)n * 512 + hc * 64 + c8 * 8);
    }
    __syncthreads();
    f32x4 h4[4];
#pragma unroll
    for (int nt = 0; nt < 4; nt++)
#pragma unroll
      for (int r = 0; r < 4; r++) h4[nt][r] = 0.f;
#pragma unroll
    for (int kc = 0; kc < 4; kc++) {
      bf16x8 a = *(const bf16x8*)(sIn + (wv * 16 + m) * LDA + kc * 32 + quad * 8);
#pragma unroll
      for (int nt = 0; nt < 4; nt++) {
        bf16x8 bb = *(const bf16x8*)(sW1 + (nt * 16 + m) * LDA + kc * 32 + quad * 8);
        h4[nt] = __builtin_amdgcn_mfma_f32_16x16x32_bf16(a, bb, h4[nt], 0, 0, 0);
      }
    }
#pragma unroll
    for (int nt = 0; nt < 4; nt++) {
      int col = nt * 16 + m;
      float bv = bf2f(b1[hc * 64 + col]);
#pragma unroll
      for (int r = 0; r < 4; r++) {
        float x = h4[nt][r] + bv;
        float gx = 0.5f * x * (1.f + erff(x * 0.70710678118654752f));
        sH[(wv * 16 + quad * 4 + r) * 72 + col] = f2bf(gx);
      }
    }
    __syncthreads();
#pragma unroll
    for (int kc = 0; kc < 2; kc++) {
      bf16x8 a = *(const bf16x8*)(sH + (wv * 16 + m) * 72 + kc * 32 + quad * 8);
#pragma unroll
      for (int nt = 0; nt < 8; nt++) {
        bf16x8 bb = *(const bf16x8*)(sW2 + (nt * 16 + m) * 72 + kc * 32 + quad * 8);
        acc2[nt] = __builtin_amdgcn_mfma_f32_16x16x32_bf16(a, bb, acc2[nt], 0, 0, 0);
      }
    }
  }
#pragma unroll
  for (int nt = 0; nt < 8; nt++) {
    int col = nt * 16 + m;
    float bv = bf2f(b2[col]);
#pragma unroll
    for (int r = 0; r < 4; r++) {
      size_t xi = (size_t)(mbase + wv * 16 + quad * 4 + r) * 128 + col;
      X[xi] = f2bf(bf2f(X[xi]) + acc2[nt][r] + bv);
    }
  }
}

// ---------------- final LN + partial pooling ----------------
__global__ __launch_bounds__(256) void k_pool(const u16* __restrict__ X, const u16* __restrict__ vec,
                                              float* __restrict__ pool) {
  __shared__ float sacc[4][128];
  const int tid = threadIdx.x, lane = tid & 63, wv = tid >> 6;
  const int b = blockIdx.x / 10, slice = blockIdx.x % 10;
  const float nw0 = bf2f(vec[VC_NFW + 2 * lane]), nb0 = bf2f(vec[VC_NFB + 2 * lane]);
  const float nw1 = bf2f(vec[VC_NFW + 2 * lane + 1]), nb1 = bf2f(vec[VC_NFB + 2 * lane + 1]);
  float a0 = 0.f, a1 = 0.f;
  for (int t = wv; t < 1200; t += 4) {
    size_t token = (size_t)b * 12000 + slice * 1200 + t;
    unsigned int u = *(const unsigned int*)(X + token * 128 + 2 * lane);
    float x0 = bf2f((u16)(u & 0xffff)), x1 = bf2f((u16)(u >> 16));
    float mean = wsum(x0 + x1) * (1.f / 128.f);
    float var = wsum(x0 * x0 + x1 * x1) * (1.f / 128.f) - mean * mean;
    float rstd = rsqrtf(var + 1e-5f);
    a0 += (x0 - mean) * rstd * nw0 + nb0;
    a1 += (x1 - mean) * rstd * nw1 + nb1;
  }
  sacc[wv][2 * lane] = a0;
  sacc[wv][2 * lane + 1] = a1;
  __syncthreads();
  if (tid < 128) {
    float s = sacc[0][tid] + sacc[1][tid] + sacc[2][tid] + sacc[3][tid];
    atomicAdd(pool + b * 128 + tid, s);
  }
}

// ---------------- head: fp32 output ----------------
__global__ __launch_bounds__(256) void k_head(const float* __restrict__ pool,
                                              const u16* __restrict__ obs,
                                              const u16* __restrict__ vec,
                                              float* __restrict__ out) {
  const int b = blockIdx.x, o = threadIdx.x;
  float acc = bf2f(vec[VC_OBIAS + o]);
  for (int i = 0; i < 128; i++)
    acc += pool[b * 128 + i] * (1.f / 12000.f) * bf2f(vec[VC_OW + i * 256 + o]);
  for (int i = 0; i < 20; i++)
    acc += bf2f(obs[(size_t)b * 132020 + 132000 + i]) * bf2f(vec[VC_OW + (128 + i) * 256 + o]);
  out[b * 256 + o] = acc;
}

extern "C" void kernel_launch(void* const* d_in, const int* in_sizes, int n_in,
                              void* d_out, int out_size, void* d_ws, size_t ws_size,
                              hipStream_t stream) {
  // adaptive layout: small buffers first
  u16* base  = (u16*)d_ws;
  int* flag  = (int*)d_ws;
  float* pool = (float*)((char*)d_ws + 16);
  u16* VEC   = base + 10000;           //     45,056
  u16* WT    = VEC + 45056;            //    393,216 (transposed weights)
  u16* OBSC  = WT + 393216;            //  4,224,640
  u16* X     = OBSC + 4224640;         // 49,152,000
  u16* QKVc  = X + 49152000;           // CW*48,000
  const long long cap = (long long)(ws_size / 2);
  const long long fixed = 10000 + 45056 + 393216 + 4224640 + 49152000;
  // CW must keep CW*125 divisible by 64: {384, 192, 64}
  int CW = 64;
  if (fixed + 384LL * 64000 <= cap)      CW = 384;
  else if (fixed + 192LL * 64000 <= cap) CW = 192;
  u16* OBc = QKVc + (size_t)CW * 48000;  // CW*16,000

  hipMemsetAsync(d_ws, 0, 16 + 32 * 128 * sizeof(float), stream);
  k_scan<<<1, 256, 0, stream>>>((const u16*)d_in[0], flag);
  k_decide<<<1, 64, 0, stream>>>(flag);

  // converts: small params
  struct CV { int idx; int off; int n; };
  const CV cvs[] = {
      {1, VC_PW, 1408},  {2, VC_PB, 128},   {3, VC_N1W, 256},  {4, VC_N1B, 256},
      {6, VC_QKVB, 768}, {9, VC_PROJB, 256},{10, VC_N2W, 256}, {11, VC_N2B, 256},
      {13, VC_B1, 1024}, {15, VC_B2, 256},  {16, VC_NFW, 128}, {17, VC_NFB, 128},
      {7, VC_RPB, 1458}, {18, VC_OW, 37888},{19, VC_OBIAS, 256}};
  for (const auto& c : cvs)
    k_conv<<<(c.n + 255) / 256, 256, 0, stream>>>(d_in[c.idx], VEC + c.off, c.n, flag);
  k_conv<<<16504, 256, 0, stream>>>(d_in[0], OBSC, 4224640, flag);
  // converts: transposed weights for MFMA (dst[n*128+k] etc.)
  for (int l = 0; l < 2; l++) {
    k_convT2<<<192, 256, 0, stream>>>(d_in[5],  WT + WT_QKV  + l * 49152, 128, 384, l * 49152, flag);
    k_convT2<<<64,  256, 0, stream>>>(d_in[8],  WT + WT_PROJ + l * 16384, 128, 128, l * 16384, flag);
    k_convT2<<<256, 256, 0, stream>>>(d_in[12], WT + WT_W1   + l * 65536, 128, 512, l * 65536, flag);
    k_convT2<<<256, 256, 0, stream>>>(d_in[14], WT + WT_W2   + l * 65536, 512, 128, l * 65536, flag);
  }

  k_patch<<<192000, 256, 0, stream>>>(OBSC, VEC, X);

  const int CR = CW * 125;  // rows per chunk (divisible by 64)
  for (int l = 0; l < 2; l++) {
    const int shift = l ? 2 : 0;
    for (int wb0 = 0; wb0 < 3072; wb0 += CW) {
      k_gemm_qkv<<<CR / 64, 256, 0, stream>>>(X, WT + WT_QKV + l * 49152,
                                              VEC + VC_QKVB + l * 384,
                                              VEC + VC_N1W + l * 128, VEC + VC_N1B + l * 128,
                                              QKVc, shift, wb0 * 125);
      k_attn<<<CW, 256, 0, stream>>>(QKVc, OBc, VEC + VC_RPB + l * 729, wb0, l);
      k_gemm_proj<<<CR / 64, 256, 0, stream>>>(OBc, WT + WT_PROJ + l * 16384,
                                               VEC + VC_PROJB + l * 128, X, shift, wb0);
    }
    k_mlp<<<6000, 256, 0, stream>>>(X, WT + WT_W1 + l * 65536, VEC + VC_B1 + l * 512,
                                    WT + WT_W2 + l * 65536, VEC + VC_B2 + l * 128,
                                    VEC + VC_N2W + l * 128, VEC + VC_N2B + l * 128);
  }

  k_pool<<<320, 256, 0, stream>>>(X, VEC, pool);
  k_head<<<32, 256, 0, stream>>>(pool, OBSC, VEC, (float*)d_out);
}

// Round 10
// 2337.378 us; speedup vs baseline: 21.7926x; 1.8841x over previous
//
#include <hip/hip_runtime.h>

typedef unsigned short u16;
typedef short bf16x8 __attribute__((ext_vector_type(8)));
typedef float f32x4 __attribute__((ext_vector_type(4)));

#define SCALE_F 0.08838834764831845f
#define LDA 136

// VEC offsets (u16 elems)
#define VC_PW    0
#define VC_PB    1408
#define VC_N1W   1536
#define VC_N1B   1792
#define VC_QKVB  2048
#define VC_PROJB 2816
#define VC_N2W   3072
#define VC_N2B   3328
#define VC_B1    3584
#define VC_B2    4608
#define VC_NFW   4864
#define VC_NFB   4992
#define VC_RPB   5120
#define VC_OW    6592
#define VC_OBIAS 44480

// WT offsets (u16 elems) — transposed weights [N][K]
#define WT_QKV  0
#define WT_PROJ 98304
#define WT_W1   131072
#define WT_W2   262144

__device__ __forceinline__ float bf2f(u16 x) {
  union { unsigned int i; float f; } v; v.i = ((unsigned int)x) << 16; return v.f;
}
__device__ __forceinline__ u16 f2bf(float f) {
  union { float f; unsigned int i; } v; v.f = f;
  unsigned int x = v.i;
  return (u16)((x + 0x7fffu + ((x >> 16) & 1u)) >> 16);
}
__device__ __forceinline__ unsigned int packbf(float a, float b) {
  return (unsigned int)f2bf(a) | ((unsigned int)f2bf(b) << 16);
}
__device__ __forceinline__ float wsum(float v) {
#pragma unroll
  for (int m = 32; m >= 1; m >>= 1) v += __shfl_xor(v, m, 64);
  return v;
}

// -------- dtype scan + decide --------
__global__ __launch_bounds__(256) void k_scan(const u16* __restrict__ raw, int* __restrict__ flag) {
  int nanc = 0, ez = 0;
  for (int i = threadIdx.x; i < 131072; i += 256) {
    u16 x = raw[i];
    if ((x & 0x7F80u) == 0x7F80u) nanc++;
    if (!(i & 1) && x == 0) ez++;
  }
  atomicAdd(&flag[1], nanc);
  atomicAdd(&flag[2], ez);
}
__global__ void k_decide(int* __restrict__ flag) {
  if (threadIdx.x == 0) flag[0] = (flag[1] > 0 || flag[2] > 49152) ? 1 : 0;
}

// -------- dual-mode converts --------
__global__ __launch_bounds__(256) void k_conv(const void* __restrict__ src, u16* __restrict__ dst,
                                              int n, const int* __restrict__ flag) {
  const int fl = *flag;
  int i = blockIdx.x * 256 + threadIdx.x;
  if (i < n) dst[i] = fl ? f2bf(((const float*)src)[i]) : ((const u16*)src)[i];
}
__global__ __launch_bounds__(256) void k_convT2(const void* __restrict__ src, u16* __restrict__ dst,
                                                int K, int N, int eoff, const int* __restrict__ flag) {
  const int fl = *flag;
  int id = blockIdx.x * 256 + threadIdx.x;
  if (id < K * N) {
    int n = id / K, k = id % K;
    dst[id] = fl ? f2bf(((const float*)src)[eoff + k * N + n])
                 : ((const u16*)src)[eoff + k * N + n];
  }
}

// ---------------- patch embed: one block per (b,d,h) row of 40 tokens ----------------
__global__ __launch_bounds__(256) void k_patch(const u16* __restrict__ obs,
                                               const u16* __restrict__ vec,
                                               u16* __restrict__ X) {
  __shared__ float vis[11][40];
  __shared__ float spw[11][128];
  __shared__ float spb[128];
  const int tid = threadIdx.x;
  const int bdh = blockIdx.x;
  const int b = bdh / 300, rem = bdh % 300;
  const int d = rem / 30, h = rem % 30;
  for (int i = tid; i < 1408; i += 256) spw[i >> 7][i & 127] = bf2f(vec[VC_PW + i]);
  if (tid < 128) spb[tid] = bf2f(vec[VC_PB + tid]);
  for (int i = tid; i < 440; i += 256) {
    int ch = i / 40, w = i % 40;
    vis[ch][w] = bf2f(obs[(size_t)b * 132020 + ((d * 11 + ch) * 30 + h) * 40 + w]);
  }
  __syncthreads();
  const size_t xbase = ((size_t)b * 12000 + d * 1200 + h * 40) * 128;
  for (int o = tid; o < 40 * 128; o += 256) {
    int w = o >> 7, c = o & 127;
    float acc = spb[c];
#pragma unroll
    for (int ch = 0; ch < 11; ch++) acc += vis[ch][w] * spw[ch][c];
    X[xbase + o] = f2bf(acc);
  }
}

// ---------------- MFMA GEMM: fused LN1+roll+gather -> QK (stride 256) + VT (transposed) ----------------
__global__ __launch_bounds__(256) void k_gemm_qkv(const u16* __restrict__ X,
                                                  const u16* __restrict__ WTp,
                                                  const u16* __restrict__ bias,
                                                  const u16* __restrict__ nw,
                                                  const u16* __restrict__ nb,
                                                  u16* __restrict__ QK, u16* __restrict__ VT,
                                                  int shift, int row_base) {
  __shared__ u16 sA[64 * LDA];
  __shared__ u16 sB[64 * LDA];
  const int tid = threadIdx.x, lane = tid & 63, wv = tid >> 6;
  const int mbase = blockIdx.x * 64;
  const float nw0 = bf2f(nw[2 * lane]), nb0 = bf2f(nb[2 * lane]);
  const float nw1 = bf2f(nw[2 * lane + 1]), nb1 = bf2f(nb[2 * lane + 1]);
  for (int r = 0; r < 16; r++) {
    int row = wv * 16 + r;
    int rowg = row_base + mbase + row;
    int win = rowg / 125, n = rowg % 125;
    int b = win / 96, winb = win % 96;
    int wd = winb / 48, wh = (winb >> 3) % 6, ww = winb & 7;
    int ld = n / 25, lh = (n / 5) % 5, lw = n % 5;
    int d = wd * 5 + ld + shift; if (d >= 10) d -= 10;
    int h = wh * 5 + lh + shift; if (h >= 30) h -= 30;
    int w2 = ww * 5 + lw + shift; if (w2 >= 40) w2 -= 40;
    const u16* xp = X + ((((size_t)b * 10 + d) * 30 + h) * 40 + w2) * 128;
    unsigned int u = *(const unsigned int*)(xp + 2 * lane);
    float x0 = bf2f((u16)(u & 0xffff)), x1 = bf2f((u16)(u >> 16));
    float mean = wsum(x0 + x1) * (1.f / 128.f);
    float var = wsum(x0 * x0 + x1 * x1) * (1.f / 128.f) - mean * mean;
    float rstd = rsqrtf(var + 1e-5f);
    float y0 = (x0 - mean) * rstd * nw0 + nb0;
    float y1 = (x1 - mean) * rstd * nw1 + nb1;
    *(unsigned int*)(sA + row * LDA + 2 * lane) = packbf(y0, y1);
  }
  const int m = lane & 15, quad = lane >> 4;
  for (int nc = 0; nc < 6; nc++) {
    __syncthreads();
#pragma unroll
    for (int i = 0; i < 4; i++) {
      int idx = tid + i * 256;
      int row = idx >> 4, c16 = idx & 15;
      *(uint4*)(sB + row * LDA + c16 * 8) =
          *(const uint4*)(WTp + (size_t)(nc * 64 + row) * 128 + c16 * 8);
    }
    __syncthreads();
    f32x4 acc[4];
#pragma unroll
    for (int nt = 0; nt < 4; nt++)
#pragma unroll
      for (int r = 0; r < 4; r++) acc[nt][r] = 0.f;
#pragma unroll
    for (int kc = 0; kc < 4; kc++) {
      bf16x8 a = *(const bf16x8*)(sA + (wv * 16 + m) * LDA + kc * 32 + quad * 8);
#pragma unroll
      for (int nt = 0; nt < 4; nt++) {
        bf16x8 bb = *(const bf16x8*)(sB + (nt * 16 + m) * LDA + kc * 32 + quad * 8);
        acc[nt] = __builtin_amdgcn_mfma_f32_16x16x32_bf16(a, bb, acc[nt], 0, 0, 0);
      }
    }
    if (nc < 4) {
#pragma unroll
      for (int nt = 0; nt < 4; nt++) {
        int col = nc * 64 + nt * 16 + m;
        float bv = bf2f(bias[col]);
        float scl = (col < 128) ? SCALE_F : 1.f;
#pragma unroll
        for (int r = 0; r < 4; r++) {
          int row = mbase + wv * 16 + quad * 4 + r;
          QK[(size_t)row * 256 + col] = f2bf((acc[nt][r] + bv) * scl);
        }
      }
    } else {
#pragma unroll
      for (int nt = 0; nt < 4; nt++) {
        int col = nc * 64 + nt * 16 + m;
        float bv = bf2f(bias[col]);
        int colv = col - 256;
#pragma unroll
        for (int r = 0; r < 4; r++) {
          int rowl = mbase + wv * 16 + quad * 4 + r;
          int winl = rowl / 125, j = rowl % 125;
          VT[(size_t)winl * 16384 + colv * 128 + j] = f2bf(acc[nt][r] + bv);
        }
      }
    }
  }
}

// ---------------- MFMA windowed attention: S^T = K·Q^T -> softmax -> O^T = VT·P ----------------
// LDS exactly 64 KiB: sK (reused for P) + sVT, both 128x128 bf16, XOR-swizzled 16B granules.
__global__ __launch_bounds__(256) void k_attn_mfma(const u16* __restrict__ QK,
                                                   const u16* __restrict__ VT,
                                                   u16* __restrict__ OB,
                                                   const u16* __restrict__ rpb,
                                                   int win_base, int boundary) {
  __shared__ u16 sK[128 * 128];
  __shared__ u16 sVT[128 * 128];
  const int tid = threadIdx.x, lane = tid & 63, wv = tid >> 6;
  const int m16 = lane & 15, quad = lane >> 4;
  const int winl = blockIdx.x;
  const int wing = win_base + winl;
  const int winb = wing % 96;
  const int wd = winb / 48, wh = (winb >> 3) % 6, ww = winb & 7;
  const u16* qkbase = QK + (size_t)winl * (125 * 256);
  const u16* vtbase = VT + (size_t)winl * 16384;
  for (int idx = tid; idx < 125 * 16; idx += 256) {
    int j = idx >> 4, g = idx & 15;
    uint4 v = *(const uint4*)(qkbase + j * 256 + 128 + g * 8);
    *(uint4*)(sK + j * 128 + (((g ^ (j & 15))) << 3)) = v;
  }
  if (tid < 48) {
    int j = 125 + tid / 16, g = tid & 15;
    uint4 z; z.x = 0; z.y = 0; z.z = 0; z.w = 0;
    *(uint4*)(sK + j * 128 + (((g ^ (j & 15))) << 3)) = z;
  }
  for (int idx = tid; idx < 128 * 16; idx += 256) {
    int c = idx >> 4, g = idx & 15;
    uint4 v = *(const uint4*)(vtbase + c * 128 + g * 8);
    *(uint4*)(sVT + c * 128 + (((g ^ (c & 15))) << 3)) = v;
  }
  __syncthreads();

  // S^T = K·Q^T : A=K (m=j), B=Q (n=q); wave owns q-tiles {2wv, 2wv+1}
  f32x4 S[2][8];
#pragma unroll
  for (int t = 0; t < 2; t++)
#pragma unroll
    for (int jt = 0; jt < 8; jt++)
#pragma unroll
      for (int r = 0; r < 4; r++) S[t][jt][r] = 0.f;
  int qrow[2];
#pragma unroll
  for (int t = 0; t < 2; t++) {
    int q = (2 * wv + t) * 16 + m16;
    qrow[t] = q > 124 ? 124 : q;
  }
#pragma unroll
  for (int kc = 0; kc < 4; kc++) {
    bf16x8 qf[2];
#pragma unroll
    for (int t = 0; t < 2; t++)
      qf[t] = *(const bf16x8*)(qkbase + qrow[t] * 256 + kc * 32 + quad * 8);
#pragma unroll
    for (int jt = 0; jt < 8; jt++) {
      int row = jt * 16 + m16;
      bf16x8 kf = *(const bf16x8*)(sK + row * 128 + ((((4 * kc + quad) ^ m16)) << 3));
#pragma unroll
      for (int t = 0; t < 2; t++)
        S[t][jt] = __builtin_amdgcn_mfma_f32_16x16x32_bf16(kf, qf[t], S[t][jt], 0, 0, 0);
    }
  }

  // bias + masks + softmax
  int ldq[2], lhq[2], lwq[2], regQ[2];
#pragma unroll
  for (int t = 0; t < 2; t++) {
    int qc = qrow[t];
    ldq[t] = qc / 25; lhq[t] = (qc / 5) % 5; lwq[t] = qc % 5;
    regQ[t] = 0;
    if (boundary) {
      int gd = wd * 5 + ldq[t], gh = wh * 5 + lhq[t], gw = ww * 5 + lwq[t];
      regQ[t] = (gd < 5 ? 0 : (gd < 8 ? 1 : 2)) * 9 + (gh < 25 ? 0 : (gh < 28 ? 1 : 2)) * 3 +
                (gw < 35 ? 0 : (gw < 38 ? 1 : 2));
    }
  }
  float mx[2] = {-1e30f, -1e30f};
#pragma unroll
  for (int jt = 0; jt < 8; jt++) {
#pragma unroll
    for (int r = 0; r < 4; r++) {
      int j = jt * 16 + quad * 4 + r;
      bool jvalid = j < 125;
      int jc = jvalid ? j : 124;
      int ldk = jc / 25, lhk = (jc / 5) % 5, lwk = jc % 5;
      int regK = 0;
      if (boundary) {
        int gd = wd * 5 + ldk, gh = wh * 5 + lhk, gw = ww * 5 + lwk;
        regK = (gd < 5 ? 0 : (gd < 8 ? 1 : 2)) * 9 + (gh < 25 ? 0 : (gh < 28 ? 1 : 2)) * 3 +
               (gw < 35 ? 0 : (gw < 38 ? 1 : 2));
      }
#pragma unroll
      for (int t = 0; t < 2; t++) {
        float s = S[t][jt][r];
        int idx = ((ldq[t] - ldk + 4) * 9 + (lhq[t] - lhk + 4)) * 9 + (lwq[t] - lwk + 4);
        s += bf2f(rpb[idx]);
        if (ldq[t] < ldk) s -= 100.f;
        if (boundary && regQ[t] != regK) s -= 100.f;
        if (!jvalid) s = -1e30f;
        S[t][jt][r] = s;
        mx[t] = fmaxf(mx[t], s);
      }
    }
  }
#pragma unroll
  for (int t = 0; t < 2; t++) {
    mx[t] = fmaxf(mx[t], __shfl_xor(mx[t], 16, 64));
    mx[t] = fmaxf(mx[t], __shfl_xor(mx[t], 32, 64));
  }
  float sm[2] = {0.f, 0.f};
#pragma unroll
  for (int jt = 0; jt < 8; jt++)
#pragma unroll
    for (int r = 0; r < 4; r++)
#pragma unroll
      for (int t = 0; t < 2; t++) {
        float e = __expf(S[t][jt][r] - mx[t]);
        S[t][jt][r] = e;
        sm[t] += e;
      }
#pragma unroll
  for (int t = 0; t < 2; t++) {
    sm[t] += __shfl_xor(sm[t], 16, 64);
    sm[t] += __shfl_xor(sm[t], 32, 64);
    sm[t] = 1.f / sm[t];
  }

  // write P into sK region (swizzled); each wave writes only its own q rows
  __syncthreads();
  u16* sP = sK;
#pragma unroll
  for (int t = 0; t < 2; t++) {
    int q = (2 * wv + t) * 16 + m16;
#pragma unroll
    for (int jt = 0; jt < 8; jt++) {
      uint2 pk;
      pk.x = packbf(S[t][jt][0] * sm[t], S[t][jt][1] * sm[t]);
      pk.y = packbf(S[t][jt][2] * sm[t], S[t][jt][3] * sm[t]);
      int phys16 = (2 * jt + (quad >> 1)) ^ m16;
      *(uint2*)(sP + q * 128 + (phys16 << 3) + ((quad & 1) << 2)) = pk;
    }
  }
  __syncthreads();

  // O^T = VT·P : A=VT (m=c), B=P (n=q)
  f32x4 O[8][2];
#pragma unroll
  for (int ct = 0; ct < 8; ct++)
#pragma unroll
    for (int t = 0; t < 2; t++)
#pragma unroll
      for (int r = 0; r < 4; r++) O[ct][t][r] = 0.f;
#pragma unroll
  for (int kc = 0; kc < 4; kc++) {
    bf16x8 pf[2];
#pragma unroll
    for (int t = 0; t < 2; t++) {
      int q = (2 * wv + t) * 16 + m16;
      pf[t] = *(const bf16x8*)(sP + q * 128 + ((((4 * kc + quad) ^ m16)) << 3));
    }
#pragma unroll
    for (int ct = 0; ct < 8; ct++) {
      int c = ct * 16 + m16;
      bf16x8 vf = *(const bf16x8*)(sVT + c * 128 + ((((4 * kc + quad) ^ m16)) << 3));
#pragma unroll
      for (int t = 0; t < 2; t++)
        O[ct][t] = __builtin_amdgcn_mfma_f32_16x16x32_bf16(vf, pf[t], O[ct][t], 0, 0, 0);
    }
  }
#pragma unroll
  for (int t = 0; t < 2; t++) {
    int q = (2 * wv + t) * 16 + m16;
    if (q < 125) {
      u16* orow = OB + ((size_t)winl * 125 + q) * 128;
#pragma unroll
      for (int ct = 0; ct < 8; ct++) {
        uint2 ok;
        ok.x = packbf(O[ct][t][0], O[ct][t][1]);
        ok.y = packbf(O[ct][t][2], O[ct][t][3]);
        *(uint2*)(orow + ct * 16 + quad * 4) = ok;
      }
    }
  }
}

// ---------------- MFMA GEMM: proj (reads OB) + roll-back + residual scatter-add ----------------
__global__ __launch_bounds__(256) void k_gemm_proj(const u16* __restrict__ In,
                                                   const u16* __restrict__ WTp,
                                                   const u16* __restrict__ bias,
                                                   u16* __restrict__ X, int shift,
                                                   int win_base) {
  __shared__ u16 sA[64 * LDA];
  __shared__ u16 sB[64 * LDA];
  const int tid = threadIdx.x;
  const int mbase = blockIdx.x * 64;
#pragma unroll
  for (int i = 0; i < 4; i++) {
    int idx = tid + i * 256;
    int row = idx >> 4, c16 = idx & 15;
    *(uint4*)(sA + row * LDA + c16 * 8) =
        *(const uint4*)(In + (size_t)(mbase + row) * 128 + c16 * 8);
  }
  const int lane = tid & 63, wv = tid >> 6;
  const int m = lane & 15, quad = lane >> 4;
  size_t xbase[4];
#pragma unroll
  for (int r = 0; r < 4; r++) {
    int rowl = mbase + wv * 16 + quad * 4 + r;
    int win = win_base + rowl / 125, n = rowl % 125;
    int b = win / 96, winb = win % 96;
    int wd = winb / 48, wh = (winb >> 3) % 6, ww = winb & 7;
    int ld = n / 25, lh = (n / 5) % 5, lw = n % 5;
    int d = wd * 5 + ld + shift; if (d >= 10) d -= 10;
    int h = wh * 5 + lh + shift; if (h >= 30) h -= 30;
    int w2 = ww * 5 + lw + shift; if (w2 >= 40) w2 -= 40;
    xbase[r] = ((((size_t)b * 10 + d) * 30 + h) * 40 + w2) * 128;
  }
  for (int nc = 0; nc < 2; nc++) {
    __syncthreads();
#pragma unroll
    for (int i = 0; i < 4; i++) {
      int idx = tid + i * 256;
      int row = idx >> 4, c16 = idx & 15;
      *(uint4*)(sB + row * LDA + c16 * 8) =
          *(const uint4*)(WTp + (size_t)(nc * 64 + row) * 128 + c16 * 8);
    }
    __syncthreads();
    f32x4 acc[4];
#pragma unroll
    for (int nt = 0; nt < 4; nt++)
#pragma unroll
      for (int r = 0; r < 4; r++) acc[nt][r] = 0.f;
#pragma unroll
    for (int kc = 0; kc < 4; kc++) {
      bf16x8 a = *(const bf16x8*)(sA + (wv * 16 + m) * LDA + kc * 32 + quad * 8);
#pragma unroll
      for (int nt = 0; nt < 4; nt++) {
        bf16x8 bb = *(const bf16x8*)(sB + (nt * 16 + m) * LDA + kc * 32 + quad * 8);
        acc[nt] = __builtin_amdgcn_mfma_f32_16x16x32_bf16(a, bb, acc[nt], 0, 0, 0);
      }
    }
#pragma unroll
    for (int nt = 0; nt < 4; nt++) {
      int col = nc * 64 + nt * 16 + m;
      float bv = bf2f(bias[col]);
#pragma unroll
      for (int r = 0; r < 4; r++) {
        size_t xi = xbase[r] + col;
        X[xi] = f2bf(bf2f(X[xi]) + acc[nt][r] + bv);
      }
    }
  }
}

// ---------------- fused LN2 + MLP + residual ----------------
__global__ __launch_bounds__(256) void k_mlp(u16* __restrict__ X, const u16* __restrict__ W1T,
                                             const u16* __restrict__ b1, const u16* __restrict__ W2T,
                                             const u16* __restrict__ b2, const u16* __restrict__ nw,
                                             const u16* __restrict__ nb) {
  __shared__ u16 sIn[64 * LDA];
  __shared__ u16 sW1[64 * LDA];
  __shared__ u16 sH[64 * 72];
  __shared__ u16 sW2[128 * 72];
  const int tid = threadIdx.x, lane = tid & 63, wv = tid >> 6;
  const int m = lane & 15, quad = lane >> 4;
  const int mbase = blockIdx.x * 64;
  const float nw0 = bf2f(nw[2 * lane]), nb0 = bf2f(nb[2 * lane]);
  const float nw1 = bf2f(nw[2 * lane + 1]), nb1 = bf2f(nb[2 * lane + 1]);
  for (int r = 0; r < 16; r++) {
    int row = wv * 16 + r;
    unsigned int u = *(const unsigned int*)(X + (size_t)(mbase + row) * 128 + 2 * lane);
    float x0 = bf2f((u16)(u & 0xffff)), x1 = bf2f((u16)(u >> 16));
    float mean = wsum(x0 + x1) * (1.f / 128.f);
    float var = wsum(x0 * x0 + x1 * x1) * (1.f / 128.f) - mean * mean;
    float rstd = rsqrtf(var + 1e-5f);
    float y0 = (x0 - mean) * rstd * nw0 + nb0;
    float y1 = (x1 - mean) * rstd * nw1 + nb1;
    *(unsigned int*)(sIn + row * LDA + 2 * lane) = packbf(y0, y1);
  }
  f32x4 acc2[8];
#pragma unroll
  for (int nt = 0; nt < 8; nt++)
#pragma unroll
    for (int r = 0; r < 4; r++) acc2[nt][r] = 0.f;
  for (int hc = 0; hc < 8; hc++) {
    __syncthreads();
#pragma unroll
    for (int i = 0; i < 4; i++) {
      int idx = tid + i * 256;
      int row = idx >> 4, c16 = idx & 15;
      *(uint4*)(sW1 + row * LDA + c16 * 8) =
          *(const uint4*)(W1T + (size_t)(hc * 64 + row) * 128 + c16 * 8);
    }
#pragma unroll
    for (int i = 0; i < 4; i++) {
      int idx = tid + i * 256;
      int n = idx >> 3, c8 = idx & 7;
      *(uint4*)(sW2 + n * 72 + c8 * 8) = *(const uint4*)(W2T + (size_t)n * 512 + hc * 64 + c8 * 8);
    }
    __syncthreads();
    f32x4 h4[4];
#pragma unroll
    for (int nt = 0; nt < 4; nt++)
#pragma unroll
      for (int r = 0; r < 4; r++) h4[nt][r] = 0.f;
#pragma unroll
    for (int kc = 0; kc < 4; kc++) {
      bf16x8 a = *(const bf16x8*)(sIn + (wv * 16 + m) * LDA + kc * 32 + quad * 8);
#pragma unroll
      for (int nt = 0; nt < 4; nt++) {
        bf16x8 bb = *(const bf16x8*)(sW1 + (nt * 16 + m) * LDA + kc * 32 + quad * 8);
        h4[nt] = __builtin_amdgcn_mfma_f32_16x16x32_bf16(a, bb, h4[nt], 0, 0, 0);
      }
    }
#pragma unroll
    for (int nt = 0; nt < 4; nt++) {
      int col = nt * 16 + m;
      float bv = bf2f(b1[hc * 64 + col]);
#pragma unroll
      for (int r = 0; r < 4; r++) {
        float x = h4[nt][r] + bv;
        float gx = 0.5f * x * (1.f + erff(x * 0.70710678118654752f));
        sH[(wv * 16 + quad * 4 + r) * 72 + col] = f2bf(gx);
      }
    }
    __syncthreads();
#pragma unroll
    for (int kc = 0; kc < 2; kc++) {
      bf16x8 a = *(const bf16x8*)(sH + (wv * 16 + m) * 72 + kc * 32 + quad * 8);
#pragma unroll
      for (int nt = 0; nt < 8; nt++) {
        bf16x8 bb = *(const bf16x8*)(sW2 + (nt * 16 + m) * 72 + kc * 32 + quad * 8);
        acc2[nt] = __builtin_amdgcn_mfma_f32_16x16x32_bf16(a, bb, acc2[nt], 0, 0, 0);
      }
    }
  }
#pragma unroll
  for (int nt = 0; nt < 8; nt++) {
    int col = nt * 16 + m;
    float bv = bf2f(b2[col]);
#pragma unroll
    for (int r = 0; r < 4; r++) {
      size_t xi = (size_t)(mbase + wv * 16 + quad * 4 + r) * 128 + col;
      X[xi] = f2bf(bf2f(X[xi]) + acc2[nt][r] + bv);
    }
  }
}

// ---------------- final LN + partial pooling ----------------
__global__ __launch_bounds__(256) void k_pool(const u16* __restrict__ X, const u16* __restrict__ vec,
                                              float* __restrict__ pool) {
  __shared__ float sacc[4][128];
  const int tid = threadIdx.x, lane = tid & 63, wv = tid >> 6;
  const int b = blockIdx.x / 10, slice = blockIdx.x % 10;
  const float nw0 = bf2f(vec[VC_NFW + 2 * lane]), nb0 = bf2f(vec[VC_NFB + 2 * lane]);
  const float nw1 = bf2f(vec[VC_NFW + 2 * lane + 1]), nb1 = bf2f(vec[VC_NFB + 2 * lane + 1]);
  float a0 = 0.f, a1 = 0.f;
  for (int t = wv; t < 1200; t += 4) {
    size_t token = (size_t)b * 12000 + slice * 1200 + t;
    unsigned int u = *(const unsigned int*)(X + token * 128 + 2 * lane);
    float x0 = bf2f((u16)(u & 0xffff)), x1 = bf2f((u16)(u >> 16));
    float mean = wsum(x0 + x1) * (1.f / 128.f);
    float var = wsum(x0 * x0 + x1 * x1) * (1.f / 128.f) - mean * mean;
    float rstd = rsqrtf(var + 1e-5f);
    a0 += (x0 - mean) * rstd * nw0 + nb0;
    a1 += (x1 - mean) * rstd * nw1 + nb1;
  }
  sacc[wv][2 * lane] = a0;
  sacc[wv][2 * lane + 1] = a1;
  __syncthreads();
  if (tid < 128) {
    float s = sacc[0][tid] + sacc[1][tid] + sacc[2][tid] + sacc[3][tid];
    atomicAdd(pool + b * 128 + tid, s);
  }
}

// ---------------- head: fp32 output ----------------
__global__ __launch_bounds__(256) void k_head(const float* __restrict__ pool,
                                              const u16* __restrict__ obs,
                                              const u16* __restrict__ vec,
                                              float* __restrict__ out) {
  const int b = blockIdx.x, o = threadIdx.x;
  float acc = bf2f(vec[VC_OBIAS + o]);
  for (int i = 0; i < 128; i++)
    acc += pool[b * 128 + i] * (1.f / 12000.f) * bf2f(vec[VC_OW + i * 256 + o]);
  for (int i = 0; i < 20; i++)
    acc += bf2f(obs[(size_t)b * 132020 + 132000 + i]) * bf2f(vec[VC_OW + (128 + i) * 256 + o]);
  out[b * 256 + o] = acc;
}

extern "C" void kernel_launch(void* const* d_in, const int* in_sizes, int n_in,
                              void* d_out, int out_size, void* d_ws, size_t ws_size,
                              hipStream_t stream) {
  u16* base  = (u16*)d_ws;
  int* flag  = (int*)d_ws;
  float* pool = (float*)((char*)d_ws + 16);
  u16* VEC   = base + 10000;
  u16* WT    = VEC + 45056;
  u16* OBSC  = WT + 393216;
  u16* X     = OBSC + 4224640;
  u16* QKc   = X + 49152000;           // CW*32000 (Q,K stride 256)
  const long long cap = (long long)(ws_size / 2);
  const long long fixed = 10000 + 45056 + 393216 + 4224640 + 49152000;
  // per-window chunk cost: QK 32000 + VT 16384 + OB 16000 = 64384 u16
  int CW = 64;
  if (fixed + 384LL * 64384 <= cap)      CW = 384;
  else if (fixed + 192LL * 64384 <= cap) CW = 192;
  u16* VTc = QKc + (size_t)CW * 32000;   // CW*16384
  u16* OBc = VTc + (size_t)CW * 16384;   // CW*16000

  hipMemsetAsync(d_ws, 0, 16 + 32 * 128 * sizeof(float), stream);
  k_scan<<<1, 256, 0, stream>>>((const u16*)d_in[0], flag);
  k_decide<<<1, 64, 0, stream>>>(flag);

  struct CV { int idx; int off; int n; };
  const CV cvs[] = {
      {1, VC_PW, 1408},  {2, VC_PB, 128},   {3, VC_N1W, 256},  {4, VC_N1B, 256},
      {6, VC_QKVB, 768}, {9, VC_PROJB, 256},{10, VC_N2W, 256}, {11, VC_N2B, 256},
      {13, VC_B1, 1024}, {15, VC_B2, 256},  {16, VC_NFW, 128}, {17, VC_NFB, 128},
      {7, VC_RPB, 1458}, {18, VC_OW, 37888},{19, VC_OBIAS, 256}};
  for (const auto& c : cvs)
    k_conv<<<(c.n + 255) / 256, 256, 0, stream>>>(d_in[c.idx], VEC + c.off, c.n, flag);
  k_conv<<<16504, 256, 0, stream>>>(d_in[0], OBSC, 4224640, flag);
  for (int l = 0; l < 2; l++) {
    k_convT2<<<192, 256, 0, stream>>>(d_in[5],  WT + WT_QKV  + l * 49152, 128, 384, l * 49152, flag);
    k_convT2<<<64,  256, 0, stream>>>(d_in[8],  WT + WT_PROJ + l * 16384, 128, 128, l * 16384, flag);
    k_convT2<<<256, 256, 0, stream>>>(d_in[12], WT + WT_W1   + l * 65536, 128, 512, l * 65536, flag);
    k_convT2<<<256, 256, 0, stream>>>(d_in[14], WT + WT_W2   + l * 65536, 512, 128, l * 65536, flag);
  }

  k_patch<<<9600, 256, 0, stream>>>(OBSC, VEC, X);

  const int CR = CW * 125;  // rows per chunk (divisible by 64 for CW in {64,192,384})
  for (int l = 0; l < 2; l++) {
    const int shift = l ? 2 : 0;
    for (int wb0 = 0; wb0 < 3072; wb0 += CW) {
      k_gemm_qkv<<<CR / 64, 256, 0, stream>>>(X, WT + WT_QKV + l * 49152,
                                              VEC + VC_QKVB + l * 384,
                                              VEC + VC_N1W + l * 128, VEC + VC_N1B + l * 128,
                                              QKc, VTc, shift, wb0 * 125);
      k_attn_mfma<<<CW, 256, 0, stream>>>(QKc, VTc, OBc, VEC + VC_RPB + l * 729, wb0, l);
      k_gemm_proj<<<CR / 64, 256, 0, stream>>>(OBc, WT + WT_PROJ + l * 16384,
                                               VEC + VC_PROJB + l * 128, X, shift, wb0);
    }
    k_mlp<<<6000, 256, 0, stream>>>(X, WT + WT_W1 + l * 65536, VEC + VC_B1 + l * 512,
                                    WT + WT_W2 + l * 65536, VEC + VC_B2 + l * 128,
                                    VEC + VC_N2W + l * 128, VEC + VC_N2B + l * 128);
  }

  k_pool<<<320, 256, 0, stream>>>(X, VEC, pool);
  k_head<<<32, 256, 0, stream>>>(pool, OBSC, VEC, (float*)d_out);
}

// Round 11
// 2314.005 us; speedup vs baseline: 22.0127x; 1.0101x over previous
//
#include <hip/hip_runtime.h>

typedef unsigned short u16;
typedef short bf16x8 __attribute__((ext_vector_type(8)));
typedef float f32x4 __attribute__((ext_vector_type(4)));

#define SCALE_F 0.08838834764831845f
#define LDA 136

// VEC offsets (u16 elems)
#define VC_PW    0
#define VC_PB    1408
#define VC_N1W   1536
#define VC_N1B   1792
#define VC_QKVB  2048
#define VC_PROJB 2816
#define VC_N2W   3072
#define VC_N2B   3328
#define VC_B1    3584
#define VC_B2    4608
#define VC_NFW   4864
#define VC_NFB   4992
#define VC_RPB   5120
#define VC_OW    6592
#define VC_OBIAS 44480

// WT offsets (u16 elems) — transposed weights [N][K]
#define WT_QKV  0
#define WT_PROJ 98304
#define WT_W1   131072
#define WT_W2   262144

__device__ __forceinline__ float bf2f(u16 x) {
  union { unsigned int i; float f; } v; v.i = ((unsigned int)x) << 16; return v.f;
}
__device__ __forceinline__ u16 f2bf(float f) {
  union { float f; unsigned int i; } v; v.f = f;
  unsigned int x = v.i;
  return (u16)((x + 0x7fffu + ((x >> 16) & 1u)) >> 16);
}
__device__ __forceinline__ unsigned int packbf(float a, float b) {
  return (unsigned int)f2bf(a) | ((unsigned int)f2bf(b) << 16);
}
__device__ __forceinline__ float wsum(float v) {
#pragma unroll
  for (int m = 32; m >= 1; m >>= 1) v += __shfl_xor(v, m, 64);
  return v;
}
// tanh-form gelu: x * sigmoid(1.59577*(x + 0.044715 x^3)); |err| <= ~3e-3, cheap
__device__ __forceinline__ float gelu_f(float x) {
  float u = -1.5957691216057308f * x * (1.f + 0.044715f * x * x);
  float e = __expf(u);
  return x * __builtin_amdgcn_rcpf(1.f + e);
}

// -------- dtype scan + decide --------
__global__ __launch_bounds__(256) void k_scan(const u16* __restrict__ raw, int* __restrict__ flag) {
  int nanc = 0, ez = 0;
  for (int i = threadIdx.x; i < 131072; i += 256) {
    u16 x = raw[i];
    if ((x & 0x7F80u) == 0x7F80u) nanc++;
    if (!(i & 1) && x == 0) ez++;
  }
  atomicAdd(&flag[1], nanc);
  atomicAdd(&flag[2], ez);
}
__global__ void k_decide(int* __restrict__ flag) {
  if (threadIdx.x == 0) flag[0] = (flag[1] > 0 || flag[2] > 49152) ? 1 : 0;
}

// -------- dual-mode converts --------
__global__ __launch_bounds__(256) void k_conv(const void* __restrict__ src, u16* __restrict__ dst,
                                              int n, const int* __restrict__ flag) {
  const int fl = *flag;
  int i = blockIdx.x * 256 + threadIdx.x;
  if (i < n) dst[i] = fl ? f2bf(((const float*)src)[i]) : ((const u16*)src)[i];
}
__global__ __launch_bounds__(256) void k_convT2(const void* __restrict__ src, u16* __restrict__ dst,
                                                int K, int N, int eoff, const int* __restrict__ flag) {
  const int fl = *flag;
  int id = blockIdx.x * 256 + threadIdx.x;
  if (id < K * N) {
    int n = id / K, k = id % K;
    dst[id] = fl ? f2bf(((const float*)src)[eoff + k * N + n])
                 : ((const u16*)src)[eoff + k * N + n];
  }
}

// ---------------- patch embed: one block per (b,d,h) row of 40 tokens ----------------
__global__ __launch_bounds__(256) void k_patch(const u16* __restrict__ obs,
                                               const u16* __restrict__ vec,
                                               u16* __restrict__ X) {
  __shared__ float vis[11][40];
  __shared__ float spw[11][128];
  __shared__ float spb[128];
  const int tid = threadIdx.x;
  const int bdh = blockIdx.x;
  const int b = bdh / 300, rem = bdh % 300;
  const int d = rem / 30, h = rem % 30;
  for (int i = tid; i < 1408; i += 256) spw[i >> 7][i & 127] = bf2f(vec[VC_PW + i]);
  if (tid < 128) spb[tid] = bf2f(vec[VC_PB + tid]);
  for (int i = tid; i < 440; i += 256) {
    int ch = i / 40, w = i % 40;
    vis[ch][w] = bf2f(obs[(size_t)b * 132020 + ((d * 11 + ch) * 30 + h) * 40 + w]);
  }
  __syncthreads();
  const size_t xbase = ((size_t)b * 12000 + d * 1200 + h * 40) * 128;
  for (int o = tid; o < 40 * 128; o += 256) {
    int w = o >> 7, c = o & 127;
    float acc = spb[c];
#pragma unroll
    for (int ch = 0; ch < 11; ch++) acc += vis[ch][w] * spw[ch][c];
    X[xbase + o] = f2bf(acc);
  }
}

// ---------------- MFMA GEMM: fused LN1+roll+gather -> QK (stride 256) + VT (transposed) ----------------
__global__ __launch_bounds__(256) void k_gemm_qkv(const u16* __restrict__ X,
                                                  const u16* __restrict__ WTp,
                                                  const u16* __restrict__ bias,
                                                  const u16* __restrict__ nw,
                                                  const u16* __restrict__ nb,
                                                  u16* __restrict__ QK, u16* __restrict__ VT,
                                                  int shift, int row_base) {
  __shared__ u16 sA[64 * LDA];
  __shared__ u16 sB[64 * LDA];
  const int tid = threadIdx.x, lane = tid & 63, wv = tid >> 6;
  const int mbase = blockIdx.x * 64;
  const float nw0 = bf2f(nw[2 * lane]), nb0 = bf2f(nb[2 * lane]);
  const float nw1 = bf2f(nw[2 * lane + 1]), nb1 = bf2f(nb[2 * lane + 1]);
  for (int r = 0; r < 16; r++) {
    int row = wv * 16 + r;
    int rowg = row_base + mbase + row;
    int win = rowg / 125, n = rowg % 125;
    int b = win / 96, winb = win % 96;
    int wd = winb / 48, wh = (winb >> 3) % 6, ww = winb & 7;
    int ld = n / 25, lh = (n / 5) % 5, lw = n % 5;
    int d = wd * 5 + ld + shift; if (d >= 10) d -= 10;
    int h = wh * 5 + lh + shift; if (h >= 30) h -= 30;
    int w2 = ww * 5 + lw + shift; if (w2 >= 40) w2 -= 40;
    const u16* xp = X + ((((size_t)b * 10 + d) * 30 + h) * 40 + w2) * 128;
    unsigned int u = *(const unsigned int*)(xp + 2 * lane);
    float x0 = bf2f((u16)(u & 0xffff)), x1 = bf2f((u16)(u >> 16));
    float mean = wsum(x0 + x1) * (1.f / 128.f);
    float var = wsum(x0 * x0 + x1 * x1) * (1.f / 128.f) - mean * mean;
    float rstd = rsqrtf(var + 1e-5f);
    float y0 = (x0 - mean) * rstd * nw0 + nb0;
    float y1 = (x1 - mean) * rstd * nw1 + nb1;
    *(unsigned int*)(sA + row * LDA + 2 * lane) = packbf(y0, y1);
  }
  const int m = lane & 15, quad = lane >> 4;
  for (int nc = 0; nc < 6; nc++) {
    __syncthreads();
#pragma unroll
    for (int i = 0; i < 4; i++) {
      int idx = tid + i * 256;
      int row = idx >> 4, c16 = idx & 15;
      *(uint4*)(sB + row * LDA + c16 * 8) =
          *(const uint4*)(WTp + (size_t)(nc * 64 + row) * 128 + c16 * 8);
    }
    __syncthreads();
    f32x4 acc[4];
#pragma unroll
    for (int nt = 0; nt < 4; nt++)
#pragma unroll
      for (int r = 0; r < 4; r++) acc[nt][r] = 0.f;
#pragma unroll
    for (int kc = 0; kc < 4; kc++) {
      bf16x8 a = *(const bf16x8*)(sA + (wv * 16 + m) * LDA + kc * 32 + quad * 8);
#pragma unroll
      for (int nt = 0; nt < 4; nt++) {
        bf16x8 bb = *(const bf16x8*)(sB + (nt * 16 + m) * LDA + kc * 32 + quad * 8);
        acc[nt] = __builtin_amdgcn_mfma_f32_16x16x32_bf16(a, bb, acc[nt], 0, 0, 0);
      }
    }
    if (nc < 4) {
#pragma unroll
      for (int nt = 0; nt < 4; nt++) {
        int col = nc * 64 + nt * 16 + m;
        float bv = bf2f(bias[col]);
        float scl = (col < 128) ? SCALE_F : 1.f;
#pragma unroll
        for (int r = 0; r < 4; r++) {
          int row = mbase + wv * 16 + quad * 4 + r;
          QK[(size_t)row * 256 + col] = f2bf((acc[nt][r] + bv) * scl);
        }
      }
    } else {
#pragma unroll
      for (int nt = 0; nt < 4; nt++) {
        int col = nc * 64 + nt * 16 + m;
        float bv = bf2f(bias[col]);
        int colv = col - 256;
#pragma unroll
        for (int r = 0; r < 4; r++) {
          int rowl = mbase + wv * 16 + quad * 4 + r;
          int winl = rowl / 125, j = rowl % 125;
          VT[(size_t)winl * 16384 + colv * 128 + j] = f2bf(acc[nt][r] + bv);
        }
      }
    }
  }
}

// ---------------- MFMA windowed attention: S^T = K·Q^T -> softmax -> O^T = VT·P ----------------
__global__ __launch_bounds__(256) void k_attn_mfma(const u16* __restrict__ QK,
                                                   const u16* __restrict__ VT,
                                                   u16* __restrict__ OB,
                                                   const u16* __restrict__ rpb,
                                                   int win_base, int boundary) {
  __shared__ u16 sK[128 * 128];
  __shared__ u16 sVT[128 * 128];
  const int tid = threadIdx.x, lane = tid & 63, wv = tid >> 6;
  const int m16 = lane & 15, quad = lane >> 4;
  const int winl = blockIdx.x;
  const int wing = win_base + winl;
  const int winb = wing % 96;
  const int wd = winb / 48, wh = (winb >> 3) % 6, ww = winb & 7;
  const u16* qkbase = QK + (size_t)winl * (125 * 256);
  const u16* vtbase = VT + (size_t)winl * 16384;
  for (int idx = tid; idx < 125 * 16; idx += 256) {
    int j = idx >> 4, g = idx & 15;
    uint4 v = *(const uint4*)(qkbase + j * 256 + 128 + g * 8);
    *(uint4*)(sK + j * 128 + (((g ^ (j & 15))) << 3)) = v;
  }
  if (tid < 48) {
    int j = 125 + tid / 16, g = tid & 15;
    uint4 z; z.x = 0; z.y = 0; z.z = 0; z.w = 0;
    *(uint4*)(sK + j * 128 + (((g ^ (j & 15))) << 3)) = z;
  }
  for (int idx = tid; idx < 128 * 16; idx += 256) {
    int c = idx >> 4, g = idx & 15;
    uint4 v = *(const uint4*)(vtbase + c * 128 + g * 8);
    *(uint4*)(sVT + c * 128 + (((g ^ (c & 15))) << 3)) = v;
  }
  __syncthreads();

  f32x4 S[2][8];
#pragma unroll
  for (int t = 0; t < 2; t++)
#pragma unroll
    for (int jt = 0; jt < 8; jt++)
#pragma unroll
      for (int r = 0; r < 4; r++) S[t][jt][r] = 0.f;
  int qrow[2];
#pragma unroll
  for (int t = 0; t < 2; t++) {
    int q = (2 * wv + t) * 16 + m16;
    qrow[t] = q > 124 ? 124 : q;
  }
#pragma unroll
  for (int kc = 0; kc < 4; kc++) {
    bf16x8 qf[2];
#pragma unroll
    for (int t = 0; t < 2; t++)
      qf[t] = *(const bf16x8*)(qkbase + qrow[t] * 256 + kc * 32 + quad * 8);
#pragma unroll
    for (int jt = 0; jt < 8; jt++) {
      int row = jt * 16 + m16;
      bf16x8 kf = *(const bf16x8*)(sK + row * 128 + ((((4 * kc + quad) ^ m16)) << 3));
#pragma unroll
      for (int t = 0; t < 2; t++)
        S[t][jt] = __builtin_amdgcn_mfma_f32_16x16x32_bf16(kf, qf[t], S[t][jt], 0, 0, 0);
    }
  }

  int ldq[2], lhq[2], lwq[2], regQ[2];
#pragma unroll
  for (int t = 0; t < 2; t++) {
    int qc = qrow[t];
    ldq[t] = qc / 25; lhq[t] = (qc / 5) % 5; lwq[t] = qc % 5;
    regQ[t] = 0;
    if (boundary) {
      int gd = wd * 5 + ldq[t], gh = wh * 5 + lhq[t], gw = ww * 5 + lwq[t];
      regQ[t] = (gd < 5 ? 0 : (gd < 8 ? 1 : 2)) * 9 + (gh < 25 ? 0 : (gh < 28 ? 1 : 2)) * 3 +
                (gw < 35 ? 0 : (gw < 38 ? 1 : 2));
    }
  }
  float mx[2] = {-1e30f, -1e30f};
#pragma unroll
  for (int jt = 0; jt < 8; jt++) {
#pragma unroll
    for (int r = 0; r < 4; r++) {
      int j = jt * 16 + quad * 4 + r;
      bool jvalid = j < 125;
      int jc = jvalid ? j : 124;
      int ldk = jc / 25, lhk = (jc / 5) % 5, lwk = jc % 5;
      int regK = 0;
      if (boundary) {
        int gd = wd * 5 + ldk, gh = wh * 5 + lhk, gw = ww * 5 + lwk;
        regK = (gd < 5 ? 0 : (gd < 8 ? 1 : 2)) * 9 + (gh < 25 ? 0 : (gh < 28 ? 1 : 2)) * 3 +
               (gw < 35 ? 0 : (gw < 38 ? 1 : 2));
      }
#pragma unroll
      for (int t = 0; t < 2; t++) {
        float s = S[t][jt][r];
        int idx = ((ldq[t] - ldk + 4) * 9 + (lhq[t] - lhk + 4)) * 9 + (lwq[t] - lwk + 4);
        s += bf2f(rpb[idx]);
        if (ldq[t] < ldk) s -= 100.f;
        if (boundary && regQ[t] != regK) s -= 100.f;
        if (!jvalid) s = -1e30f;
        S[t][jt][r] = s;
        mx[t] = fmaxf(mx[t], s);
      }
    }
  }
#pragma unroll
  for (int t = 0; t < 2; t++) {
    mx[t] = fmaxf(mx[t], __shfl_xor(mx[t], 16, 64));
    mx[t] = fmaxf(mx[t], __shfl_xor(mx[t], 32, 64));
  }
  float sm[2] = {0.f, 0.f};
#pragma unroll
  for (int jt = 0; jt < 8; jt++)
#pragma unroll
    for (int r = 0; r < 4; r++)
#pragma unroll
      for (int t = 0; t < 2; t++) {
        float e = __expf(S[t][jt][r] - mx[t]);
        S[t][jt][r] = e;
        sm[t] += e;
      }
#pragma unroll
  for (int t = 0; t < 2; t++) {
    sm[t] += __shfl_xor(sm[t], 16, 64);
    sm[t] += __shfl_xor(sm[t], 32, 64);
    sm[t] = 1.f / sm[t];
  }

  __syncthreads();
  u16* sP = sK;
#pragma unroll
  for (int t = 0; t < 2; t++) {
    int q = (2 * wv + t) * 16 + m16;
#pragma unroll
    for (int jt = 0; jt < 8; jt++) {
      uint2 pk;
      pk.x = packbf(S[t][jt][0] * sm[t], S[t][jt][1] * sm[t]);
      pk.y = packbf(S[t][jt][2] * sm[t], S[t][jt][3] * sm[t]);
      int phys16 = (2 * jt + (quad >> 1)) ^ m16;
      *(uint2*)(sP + q * 128 + (phys16 << 3) + ((quad & 1) << 2)) = pk;
    }
  }
  __syncthreads();

  f32x4 O[8][2];
#pragma unroll
  for (int ct = 0; ct < 8; ct++)
#pragma unroll
    for (int t = 0; t < 2; t++)
#pragma unroll
      for (int r = 0; r < 4; r++) O[ct][t][r] = 0.f;
#pragma unroll
  for (int kc = 0; kc < 4; kc++) {
    bf16x8 pf[2];
#pragma unroll
    for (int t = 0; t < 2; t++) {
      int q = (2 * wv + t) * 16 + m16;
      pf[t] = *(const bf16x8*)(sP + q * 128 + ((((4 * kc + quad) ^ m16)) << 3));
    }
#pragma unroll
    for (int ct = 0; ct < 8; ct++) {
      int c = ct * 16 + m16;
      bf16x8 vf = *(const bf16x8*)(sVT + c * 128 + ((((4 * kc + quad) ^ m16)) << 3));
#pragma unroll
      for (int t = 0; t < 2; t++)
        O[ct][t] = __builtin_amdgcn_mfma_f32_16x16x32_bf16(vf, pf[t], O[ct][t], 0, 0, 0);
    }
  }
#pragma unroll
  for (int t = 0; t < 2; t++) {
    int q = (2 * wv + t) * 16 + m16;
    if (q < 125) {
      u16* orow = OB + ((size_t)winl * 125 + q) * 128;
#pragma unroll
      for (int ct = 0; ct < 8; ct++) {
        uint2 ok;
        ok.x = packbf(O[ct][t][0], O[ct][t][1]);
        ok.y = packbf(O[ct][t][2], O[ct][t][3]);
        *(uint2*)(orow + ct * 16 + quad * 4) = ok;
      }
    }
  }
}

// ---------------- MFMA GEMM: proj (reads OB) + roll-back + residual scatter-add ----------------
__global__ __launch_bounds__(256) void k_gemm_proj(const u16* __restrict__ In,
                                                   const u16* __restrict__ WTp,
                                                   const u16* __restrict__ bias,
                                                   u16* __restrict__ X, int shift,
                                                   int win_base) {
  __shared__ u16 sA[64 * LDA];
  __shared__ u16 sB[64 * LDA];
  const int tid = threadIdx.x;
  const int mbase = blockIdx.x * 64;
#pragma unroll
  for (int i = 0; i < 4; i++) {
    int idx = tid + i * 256;
    int row = idx >> 4, c16 = idx & 15;
    *(uint4*)(sA + row * LDA + c16 * 8) =
        *(const uint4*)(In + (size_t)(mbase + row) * 128 + c16 * 8);
  }
  const int lane = tid & 63, wv = tid >> 6;
  const int m = lane & 15, quad = lane >> 4;
  size_t xbase[4];
#pragma unroll
  for (int r = 0; r < 4; r++) {
    int rowl = mbase + wv * 16 + quad * 4 + r;
    int win = win_base + rowl / 125, n = rowl % 125;
    int b = win / 96, winb = win % 96;
    int wd = winb / 48, wh = (winb >> 3) % 6, ww = winb & 7;
    int ld = n / 25, lh = (n / 5) % 5, lw = n % 5;
    int d = wd * 5 + ld + shift; if (d >= 10) d -= 10;
    int h = wh * 5 + lh + shift; if (h >= 30) h -= 30;
    int w2 = ww * 5 + lw + shift; if (w2 >= 40) w2 -= 40;
    xbase[r] = ((((size_t)b * 10 + d) * 30 + h) * 40 + w2) * 128;
  }
  for (int nc = 0; nc < 2; nc++) {
    __syncthreads();
#pragma unroll
    for (int i = 0; i < 4; i++) {
      int idx = tid + i * 256;
      int row = idx >> 4, c16 = idx & 15;
      *(uint4*)(sB + row * LDA + c16 * 8) =
          *(const uint4*)(WTp + (size_t)(nc * 64 + row) * 128 + c16 * 8);
    }
    __syncthreads();
    f32x4 acc[4];
#pragma unroll
    for (int nt = 0; nt < 4; nt++)
#pragma unroll
      for (int r = 0; r < 4; r++) acc[nt][r] = 0.f;
#pragma unroll
    for (int kc = 0; kc < 4; kc++) {
      bf16x8 a = *(const bf16x8*)(sA + (wv * 16 + m) * LDA + kc * 32 + quad * 8);
#pragma unroll
      for (int nt = 0; nt < 4; nt++) {
        bf16x8 bb = *(const bf16x8*)(sB + (nt * 16 + m) * LDA + kc * 32 + quad * 8);
        acc[nt] = __builtin_amdgcn_mfma_f32_16x16x32_bf16(a, bb, acc[nt], 0, 0, 0);
      }
    }
#pragma unroll
    for (int nt = 0; nt < 4; nt++) {
      int col = nc * 64 + nt * 16 + m;
      float bv = bf2f(bias[col]);
#pragma unroll
      for (int r = 0; r < 4; r++) {
        size_t xi = xbase[r] + col;
        X[xi] = f2bf(bf2f(X[xi]) + acc[nt][r] + bv);
      }
    }
  }
}

// ---------------- k_mlp v2: register-blocked transposed MLP ----------------
// 512 threads, 256 tokens/block, wave owns 32 tokens. All LDS XOR-swizzled (16B granules).
// fc1: H^T = W1T·Y^T (lane gets 4 consecutive h per token -> gelu -> ds_write_b64)
// fc2: Out^T = W2T·H^T (lane gets 4 consecutive out-ch per token -> uint2 RMW on X)
__global__ __launch_bounds__(512) void k_mlp(u16* __restrict__ X, const u16* __restrict__ W1T,
                                             const u16* __restrict__ b1, const u16* __restrict__ W2T,
                                             const u16* __restrict__ b2, const u16* __restrict__ nw,
                                             const u16* __restrict__ nb) {
  __shared__ u16 sIn[256 * 128];   // 64 KB  [token][c] swizzled
  __shared__ u16 sW1[64 * 128];    // 16 KB  [h][c] swizzled
  __shared__ u16 sH[256 * 64];     // 32 KB  [token][h] swizzled
  __shared__ u16 sW2[128 * 64];    // 16 KB  [outc][h] swizzled
  const int tid = threadIdx.x, lane = tid & 63, wv = tid >> 6;
  const int m16 = lane & 15, quad = lane >> 4;
  const int mbase = blockIdx.x * 256;
  const float nw0 = bf2f(nw[2 * lane]), nb0 = bf2f(nb[2 * lane]);
  const float nw1 = bf2f(nw[2 * lane + 1]), nb1 = bf2f(nb[2 * lane + 1]);
  // LN: wave handles its own 32 rows
  for (int r = 0; r < 32; r++) {
    int row = wv * 32 + r;
    unsigned int u = *(const unsigned int*)(X + (size_t)(mbase + row) * 128 + 2 * lane);
    float x0 = bf2f((u16)(u & 0xffff)), x1 = bf2f((u16)(u >> 16));
    float mean = wsum(x0 + x1) * (1.f / 128.f);
    float var = wsum(x0 * x0 + x1 * x1) * (1.f / 128.f) - mean * mean;
    float rstd = rsqrtf(var + 1e-5f);
    float y0 = (x0 - mean) * rstd * nw0 + nb0;
    float y1 = (x1 - mean) * rstd * nw1 + nb1;
    *(unsigned int*)(sIn + row * 128 + (((lane >> 2) ^ (row & 15)) << 3) + ((2 * lane) & 7)) =
        packbf(y0, y1);
  }
  f32x4 acc2[8][2];
#pragma unroll
  for (int mt = 0; mt < 8; mt++)
#pragma unroll
    for (int t = 0; t < 2; t++)
#pragma unroll
      for (int r = 0; r < 4; r++) acc2[mt][t][r] = 0.f;
  __syncthreads();
  for (int hc = 0; hc < 8; hc++) {
    // stage W1 chunk [64 h][128 c] and W2 chunk [128 outc][64 h]
    for (int idx = tid; idx < 1024; idx += 512) {
      int row = idx >> 4, g = idx & 15;
      uint4 v = *(const uint4*)(W1T + (size_t)(hc * 64 + row) * 128 + g * 8);
      *(uint4*)(sW1 + row * 128 + ((g ^ (row & 15)) << 3)) = v;
    }
    for (int idx = tid; idx < 1024; idx += 512) {
      int row = idx >> 3, g = idx & 7;
      uint4 v = *(const uint4*)(W2T + (size_t)row * 512 + hc * 64 + g * 8);
      *(uint4*)(sW2 + row * 64 + ((g ^ (row & 7)) << 3)) = v;
    }
    __syncthreads();
    // fc1^T: h tiles nt(4) x token tiles t(2)
    f32x4 h4[4][2];
#pragma unroll
    for (int nt = 0; nt < 4; nt++)
#pragma unroll
      for (int t = 0; t < 2; t++)
#pragma unroll
        for (int r = 0; r < 4; r++) h4[nt][t][r] = 0.f;
#pragma unroll
    for (int kc = 0; kc < 4; kc++) {
      bf16x8 bi[2];
#pragma unroll
      for (int t = 0; t < 2; t++) {
        int row = wv * 32 + t * 16 + m16;
        bi[t] = *(const bf16x8*)(sIn + row * 128 + (((4 * kc + quad) ^ m16) << 3));
      }
#pragma unroll
      for (int nt = 0; nt < 4; nt++) {
        int hrow = nt * 16 + m16;
        bf16x8 af = *(const bf16x8*)(sW1 + hrow * 128 + (((4 * kc + quad) ^ m16) << 3));
#pragma unroll
        for (int t = 0; t < 2; t++)
          h4[nt][t] = __builtin_amdgcn_mfma_f32_16x16x32_bf16(af, bi[t], h4[nt][t], 0, 0, 0);
      }
    }
    __syncthreads();  // prior fc2 done reading sH (and sW2 re-stage next iter is fenced below)
#pragma unroll
    for (int nt = 0; nt < 4; nt++) {
      int hb = nt * 16 + quad * 4;
      float bv0 = bf2f(b1[hc * 64 + hb]);
      float bv1 = bf2f(b1[hc * 64 + hb + 1]);
      float bv2 = bf2f(b1[hc * 64 + hb + 2]);
      float bv3 = bf2f(b1[hc * 64 + hb + 3]);
#pragma unroll
      for (int t = 0; t < 2; t++) {
        int tok = wv * 32 + t * 16 + m16;
        float g0 = gelu_f(h4[nt][t][0] + bv0);
        float g1 = gelu_f(h4[nt][t][1] + bv1);
        float g2 = gelu_f(h4[nt][t][2] + bv2);
        float g3 = gelu_f(h4[nt][t][3] + bv3);
        uint2 pk;
        pk.x = packbf(g0, g1);
        pk.y = packbf(g2, g3);
        int g16 = (2 * nt + (quad >> 1)) ^ (tok & 7);
        *(uint2*)(sH + tok * 64 + (g16 << 3) + ((quad & 1) << 2)) = pk;
      }
    }
    __syncthreads();
    // fc2^T: outc tiles mt(8) x token tiles t(2), K = 64 hidden (kc 0..1)
#pragma unroll
    for (int kc = 0; kc < 2; kc++) {
      bf16x8 bh[2];
#pragma unroll
      for (int t = 0; t < 2; t++) {
        int tok = wv * 32 + t * 16 + m16;
        bh[t] = *(const bf16x8*)(sH + tok * 64 + ((((4 * kc + quad) ^ (tok & 7))) << 3));
      }
#pragma unroll
      for (int mt = 0; mt < 8; mt++) {
        int oc = mt * 16 + m16;
        bf16x8 af = *(const bf16x8*)(sW2 + oc * 64 + ((((4 * kc + quad) ^ (oc & 7))) << 3));
#pragma unroll
        for (int t = 0; t < 2; t++)
          acc2[mt][t] = __builtin_amdgcn_mfma_f32_16x16x32_bf16(af, bh[t], acc2[mt][t], 0, 0, 0);
      }
    }
    __syncthreads();  // fence before next-iteration staging overwrites sW1/sW2/sH
  }
  // epilogue: residual RMW, lane holds 4 consecutive out-channels per token
#pragma unroll
  for (int mt = 0; mt < 8; mt++) {
    int oc0 = mt * 16 + quad * 4;
    float bv0 = bf2f(b2[oc0]), bv1 = bf2f(b2[oc0 + 1]);
    float bv2 = bf2f(b2[oc0 + 2]), bv3 = bf2f(b2[oc0 + 3]);
#pragma unroll
    for (int t = 0; t < 2; t++) {
      int token = mbase + wv * 32 + t * 16 + m16;
      u16* xp = X + (size_t)token * 128 + oc0;
      uint2 old = *(uint2*)xp;
      float f0 = bf2f((u16)(old.x & 0xffff)) + acc2[mt][t][0] + bv0;
      float f1 = bf2f((u16)(old.x >> 16)) + acc2[mt][t][1] + bv1;
      float f2 = bf2f((u16)(old.y & 0xffff)) + acc2[mt][t][2] + bv2;
      float f3 = bf2f((u16)(old.y >> 16)) + acc2[mt][t][3] + bv3;
      uint2 nw2;
      nw2.x = packbf(f0, f1);
      nw2.y = packbf(f2, f3);
      *(uint2*)xp = nw2;
    }
  }
}

// ---------------- final LN + partial pooling ----------------
__global__ __launch_bounds__(256) void k_pool(const u16* __restrict__ X, const u16* __restrict__ vec,
                                              float* __restrict__ pool) {
  __shared__ float sacc[4][128];
  const int tid = threadIdx.x, lane = tid & 63, wv = tid >> 6;
  const int b = blockIdx.x / 10, slice = blockIdx.x % 10;
  const float nw0 = bf2f(vec[VC_NFW + 2 * lane]), nb0 = bf2f(vec[VC_NFB + 2 * lane]);
  const float nw1 = bf2f(vec[VC_NFW + 2 * lane + 1]), nb1 = bf2f(vec[VC_NFB + 2 * lane + 1]);
  float a0 = 0.f, a1 = 0.f;
  for (int t = wv; t < 1200; t += 4) {
    size_t token = (size_t)b * 12000 + slice * 1200 + t;
    unsigned int u = *(const unsigned int*)(X + token * 128 + 2 * lane);
    float x0 = bf2f((u16)(u & 0xffff)), x1 = bf2f((u16)(u >> 16));
    float mean = wsum(x0 + x1) * (1.f / 128.f);
    float var = wsum(x0 * x0 + x1 * x1) * (1.f / 128.f) - mean * mean;
    float rstd = rsqrtf(var + 1e-5f);
    a0 += (x0 - mean) * rstd * nw0 + nb0;
    a1 += (x1 - mean) * rstd * nw1 + nb1;
  }
  sacc[wv][2 * lane] = a0;
  sacc[wv][2 * lane + 1] = a1;
  __syncthreads();
  if (tid < 128) {
    float s = sacc[0][tid] + sacc[1][tid] + sacc[2][tid] + sacc[3][tid];
    atomicAdd(pool + b * 128 + tid, s);
  }
}

// ---------------- head: fp32 output ----------------
__global__ __launch_bounds__(256) void k_head(const float* __restrict__ pool,
                                              const u16* __restrict__ obs,
                                              const u16* __restrict__ vec,
                                              float* __restrict__ out) {
  const int b = blockIdx.x, o = threadIdx.x;
  float acc = bf2f(vec[VC_OBIAS + o]);
  for (int i = 0; i < 128; i++)
    acc += pool[b * 128 + i] * (1.f / 12000.f) * bf2f(vec[VC_OW + i * 256 + o]);
  for (int i = 0; i < 20; i++)
    acc += bf2f(obs[(size_t)b * 132020 + 132000 + i]) * bf2f(vec[VC_OW + (128 + i) * 256 + o]);
  out[b * 256 + o] = acc;
}

extern "C" void kernel_launch(void* const* d_in, const int* in_sizes, int n_in,
                              void* d_out, int out_size, void* d_ws, size_t ws_size,
                              hipStream_t stream) {
  u16* base  = (u16*)d_ws;
  int* flag  = (int*)d_ws;
  float* pool = (float*)((char*)d_ws + 16);
  u16* VEC   = base + 10000;
  u16* WT    = VEC + 45056;
  u16* OBSC  = WT + 393216;
  u16* X     = OBSC + 4224640;
  u16* QKc   = X + 49152000;
  const long long cap = (long long)(ws_size / 2);
  const long long fixed = 10000 + 45056 + 393216 + 4224640 + 49152000;
  int CW = 64;
  if (fixed + 384LL * 64384 <= cap)      CW = 384;
  else if (fixed + 192LL * 64384 <= cap) CW = 192;
  u16* VTc = QKc + (size_t)CW * 32000;
  u16* OBc = VTc + (size_t)CW * 16384;

  hipMemsetAsync(d_ws, 0, 16 + 32 * 128 * sizeof(float), stream);
  k_scan<<<1, 256, 0, stream>>>((const u16*)d_in[0], flag);
  k_decide<<<1, 64, 0, stream>>>(flag);

  struct CV { int idx; int off; int n; };
  const CV cvs[] = {
      {1, VC_PW, 1408},  {2, VC_PB, 128},   {3, VC_N1W, 256},  {4, VC_N1B, 256},
      {6, VC_QKVB, 768}, {9, VC_PROJB, 256},{10, VC_N2W, 256}, {11, VC_N2B, 256},
      {13, VC_B1, 1024}, {15, VC_B2, 256},  {16, VC_NFW, 128}, {17, VC_NFB, 128},
      {7, VC_RPB, 1458}, {18, VC_OW, 37888},{19, VC_OBIAS, 256}};
  for (const auto& c : cvs)
    k_conv<<<(c.n + 255) / 256, 256, 0, stream>>>(d_in[c.idx], VEC + c.off, c.n, flag);
  k_conv<<<16504, 256, 0, stream>>>(d_in[0], OBSC, 4224640, flag);
  for (int l = 0; l < 2; l++) {
    k_convT2<<<192, 256, 0, stream>>>(d_in[5],  WT + WT_QKV  + l * 49152, 128, 384, l * 49152, flag);
    k_convT2<<<64,  256, 0, stream>>>(d_in[8],  WT + WT_PROJ + l * 16384, 128, 128, l * 16384, flag);
    k_convT2<<<256, 256, 0, stream>>>(d_in[12], WT + WT_W1   + l * 65536, 128, 512, l * 65536, flag);
    k_convT2<<<256, 256, 0, stream>>>(d_in[14], WT + WT_W2   + l * 65536, 512, 128, l * 65536, flag);
  }

  k_patch<<<9600, 256, 0, stream>>>(OBSC, VEC, X);

  const int CR = CW * 125;
  for (int l = 0; l < 2; l++) {
    const int shift = l ? 2 : 0;
    for (int wb0 = 0; wb0 < 3072; wb0 += CW) {
      k_gemm_qkv<<<CR / 64, 256, 0, stream>>>(X, WT + WT_QKV + l * 49152,
                                              VEC + VC_QKVB + l * 384,
                                              VEC + VC_N1W + l * 128, VEC + VC_N1B + l * 128,
                                              QKc, VTc, shift, wb0 * 125);
      k_attn_mfma<<<CW, 256, 0, stream>>>(QKc, VTc, OBc, VEC + VC_RPB + l * 729, wb0, l);
      k_gemm_proj<<<CR / 64, 256, 0, stream>>>(OBc, WT + WT_PROJ + l * 16384,
                                               VEC + VC_PROJB + l * 128, X, shift, wb0);
    }
    k_mlp<<<1500, 512, 0, stream>>>(X, WT + WT_W1 + l * 65536, VEC + VC_B1 + l * 512,
                                    WT + WT_W2 + l * 65536, VEC + VC_B2 + l * 128,
                                    VEC + VC_N2W + l * 128, VEC + VC_N2B + l * 128);
  }

  k_pool<<<320, 256, 0, stream>>>(X, VEC, pool);
  k_head<<<32, 256, 0, stream>>>(pool, OBSC, VEC, (float*)d_out);
}

// Round 12
// 2243.471 us; speedup vs baseline: 22.7048x; 1.0314x over previous
//
#include <hip/hip_runtime.h>

typedef unsigned short u16;
typedef short bf16x8 __attribute__((ext_vector_type(8)));
typedef float f32x4 __attribute__((ext_vector_type(4)));

#define SCALE_F 0.08838834764831845f

// VEC offsets (u16 elems)
#define VC_PW    0
#define VC_PB    1408
#define VC_N1W   1536
#define VC_N1B   1792
#define VC_QKVB  2048
#define VC_PROJB 2816
#define VC_N2W   3072
#define VC_N2B   3328
#define VC_B1    3584
#define VC_B2    4608
#define VC_NFW   4864
#define VC_NFB   4992
#define VC_RPB   5120
#define VC_OW    6592
#define VC_OBIAS 44480

// WT offsets (u16 elems) — transposed weights [N][K]
#define WT_QKV  0
#define WT_PROJ 98304
#define WT_W1   131072
#define WT_W2   262144

__device__ __forceinline__ float bf2f(u16 x) {
  union { unsigned int i; float f; } v; v.i = ((unsigned int)x) << 16; return v.f;
}
__device__ __forceinline__ u16 f2bf(float f) {
  union { float f; unsigned int i; } v; v.f = f;
  unsigned int x = v.i;
  return (u16)((x + 0x7fffu + ((x >> 16) & 1u)) >> 16);
}
__device__ __forceinline__ unsigned int packbf(float a, float b) {
  return (unsigned int)f2bf(a) | ((unsigned int)f2bf(b) << 16);
}
__device__ __forceinline__ float wsum(float v) {
#pragma unroll
  for (int m = 32; m >= 1; m >>= 1) v += __shfl_xor(v, m, 64);
  return v;
}
__device__ __forceinline__ float gelu_f(float x) {
  float u = -1.5957691216057308f * x * (1.f + 0.044715f * x * x);
  float e = __expf(u);
  return x * __builtin_amdgcn_rcpf(1.f + e);
}

// -------- dtype scan + decide --------
__global__ __launch_bounds__(256) void k_scan(const u16* __restrict__ raw, int* __restrict__ flag) {
  int nanc = 0, ez = 0;
  for (int i = threadIdx.x; i < 131072; i += 256) {
    u16 x = raw[i];
    if ((x & 0x7F80u) == 0x7F80u) nanc++;
    if (!(i & 1) && x == 0) ez++;
  }
  atomicAdd(&flag[1], nanc);
  atomicAdd(&flag[2], ez);
}
__global__ void k_decide(int* __restrict__ flag) {
  if (threadIdx.x == 0) flag[0] = (flag[1] > 0 || flag[2] > 49152) ? 1 : 0;
}

// -------- dual-mode converts --------
__global__ __launch_bounds__(256) void k_conv(const void* __restrict__ src, u16* __restrict__ dst,
                                              int n, const int* __restrict__ flag) {
  const int fl = *flag;
  int i = blockIdx.x * 256 + threadIdx.x;
  if (i < n) dst[i] = fl ? f2bf(((const float*)src)[i]) : ((const u16*)src)[i];
}
__global__ __launch_bounds__(256) void k_convT2(const void* __restrict__ src, u16* __restrict__ dst,
                                                int K, int N, int eoff, const int* __restrict__ flag) {
  const int fl = *flag;
  int id = blockIdx.x * 256 + threadIdx.x;
  if (id < K * N) {
    int n = id / K, k = id % K;
    dst[id] = fl ? f2bf(((const float*)src)[eoff + k * N + n])
                 : ((const u16*)src)[eoff + k * N + n];
  }
}

// ---------------- patch embed ----------------
__global__ __launch_bounds__(256) void k_patch(const u16* __restrict__ obs,
                                               const u16* __restrict__ vec,
                                               u16* __restrict__ X) {
  __shared__ float vis[11][40];
  __shared__ float spw[11][128];
  __shared__ float spb[128];
  const int tid = threadIdx.x;
  const int bdh = blockIdx.x;
  const int b = bdh / 300, rem = bdh % 300;
  const int d = rem / 30, h = rem % 30;
  for (int i = tid; i < 1408; i += 256) spw[i >> 7][i & 127] = bf2f(vec[VC_PW + i]);
  if (tid < 128) spb[tid] = bf2f(vec[VC_PB + tid]);
  for (int i = tid; i < 440; i += 256) {
    int ch = i / 40, w = i % 40;
    vis[ch][w] = bf2f(obs[(size_t)b * 132020 + ((d * 11 + ch) * 30 + h) * 40 + w]);
  }
  __syncthreads();
  const size_t xbase = ((size_t)b * 12000 + d * 1200 + h * 40) * 128;
  for (int o = tid; o < 40 * 128; o += 256) {
    int w = o >> 7, c = o & 127;
    float acc = spb[c];
#pragma unroll
    for (int ch = 0; ch < 11; ch++) acc += vis[ch][w] * spw[ch][c];
    X[xbase + o] = f2bf(acc);
  }
}

// ================== fused per-window: LN1 + QKV + attention + proj + residual ==================
// One block per window (3072), 512 threads (8 waves), 96 KB LDS.
// Window owns a DISJOINT set of 125 tokens -> LN-read then proj-scatter-add on X is race-free.
__global__ __launch_bounds__(512) void k_win(u16* __restrict__ X,
                                             const u16* __restrict__ Wqkv,   // [384][128]
                                             const u16* __restrict__ Wproj,  // [128][128]
                                             const u16* __restrict__ qkvb,
                                             const u16* __restrict__ projb,
                                             const u16* __restrict__ nw, const u16* __restrict__ nb,
                                             const u16* __restrict__ rpb,
                                             int shift, int boundary) {
  __shared__ u16 sY[128 * 128];   // LN'd input -> becomes Q
  __shared__ u16 sK[128 * 128];   // K -> becomes P
  __shared__ u16 sVT[128 * 128];  // V^T -> becomes O
  const int tid = threadIdx.x, lane = tid & 63, wv = tid >> 6;
  const int m16 = lane & 15, quad = lane >> 4;
  const int wing = blockIdx.x;
  const int b = wing / 96, winb = wing % 96;
  const int wd = winb / 48, wh = (winb >> 3) % 6, ww = winb & 7;
  const int tok = wv * 16 + m16;          // lane's token (0..127)
  const int tokc = tok > 124 ? 124 : tok;

  // ---- LN + roll + gather: wave handles its own 16 rows ----
  const float nw0 = bf2f(nw[2 * lane]), nb0 = bf2f(nb[2 * lane]);
  const float nw1 = bf2f(nw[2 * lane + 1]), nb1 = bf2f(nb[2 * lane + 1]);
  for (int r = 0; r < 16; r++) {
    int row = wv * 16 + r;
    int n = row > 124 ? 124 : row;
    int ld = n / 25, lh = (n / 5) % 5, lw = n % 5;
    int d = wd * 5 + ld + shift; if (d >= 10) d -= 10;
    int h = wh * 5 + lh + shift; if (h >= 30) h -= 30;
    int w2 = ww * 5 + lw + shift; if (w2 >= 40) w2 -= 40;
    const u16* xp = X + ((((size_t)b * 10 + d) * 30 + h) * 40 + w2) * 128;
    unsigned int u = *(const unsigned int*)(xp + 2 * lane);
    float x0 = bf2f((u16)(u & 0xffff)), x1 = bf2f((u16)(u >> 16));
    float mean = wsum(x0 + x1) * (1.f / 128.f);
    float var = wsum(x0 * x0 + x1 * x1) * (1.f / 128.f) - mean * mean;
    float rstd = rsqrtf(var + 1e-5f);
    float y0 = (x0 - mean) * rstd * nw0 + nb0;
    float y1 = (x1 - mean) * rstd * nw1 + nb1;
    *(unsigned int*)(sY + row * 128 + (((lane >> 2) ^ (row & 15)) << 3) + ((2 * lane) & 7)) =
        packbf(y0, y1);
  }
  // B-fragments of this wave's own token rows (no barrier: own-row write->read)
  bf16x8 biY[4];
#pragma unroll
  for (int kc = 0; kc < 4; kc++)
    biY[kc] = *(const bf16x8*)(sY + tok * 128 + (((4 * kc + quad) ^ m16) << 3));

  // ---- K -> sK[tok][ch] ----
#pragma unroll
  for (int mt = 0; mt < 8; mt++) {
    f32x4 acc; acc[0] = 0.f; acc[1] = 0.f; acc[2] = 0.f; acc[3] = 0.f;
#pragma unroll
    for (int kc = 0; kc < 4; kc++) {
      bf16x8 a = *(const bf16x8*)(Wqkv + (size_t)(128 + mt * 16 + m16) * 128 + kc * 32 + quad * 8);
      acc = __builtin_amdgcn_mfma_f32_16x16x32_bf16(a, biY[kc], acc, 0, 0, 0);
    }
    int oc = mt * 16 + quad * 4;
    uint2 pk;
    pk.x = packbf(acc[0] + bf2f(qkvb[128 + oc]), acc[1] + bf2f(qkvb[128 + oc + 1]));
    pk.y = packbf(acc[2] + bf2f(qkvb[128 + oc + 2]), acc[3] + bf2f(qkvb[128 + oc + 3]));
    *(uint2*)(sK + tok * 128 + (((2 * mt + (quad >> 1)) ^ m16) << 3) + ((quad & 1) << 2)) = pk;
  }
  // ---- V -> sVT[c][tok] ----
#pragma unroll
  for (int mt = 0; mt < 8; mt++) {
    f32x4 acc; acc[0] = 0.f; acc[1] = 0.f; acc[2] = 0.f; acc[3] = 0.f;
#pragma unroll
    for (int kc = 0; kc < 4; kc++) {
      bf16x8 a = *(const bf16x8*)(Wqkv + (size_t)(256 + mt * 16 + m16) * 128 + kc * 32 + quad * 8);
      acc = __builtin_amdgcn_mfma_f32_16x16x32_bf16(a, biY[kc], acc, 0, 0, 0);
    }
#pragma unroll
    for (int r = 0; r < 4; r++) {
      int c = mt * 16 + quad * 4 + r;
      sVT[c * 128 + ((((tok >> 3) ^ (c & 15))) << 3) + (tok & 7)] = f2bf(acc[r] + bf2f(qkvb[256 + c]));
    }
  }
  // ---- Q -> sY in place (scaled); biY already cached ----
#pragma unroll
  for (int mt = 0; mt < 8; mt++) {
    f32x4 acc; acc[0] = 0.f; acc[1] = 0.f; acc[2] = 0.f; acc[3] = 0.f;
#pragma unroll
    for (int kc = 0; kc < 4; kc++) {
      bf16x8 a = *(const bf16x8*)(Wqkv + (size_t)(mt * 16 + m16) * 128 + kc * 32 + quad * 8);
      acc = __builtin_amdgcn_mfma_f32_16x16x32_bf16(a, biY[kc], acc, 0, 0, 0);
    }
    int oc = mt * 16 + quad * 4;
    uint2 pk;
    pk.x = packbf((acc[0] + bf2f(qkvb[oc])) * SCALE_F, (acc[1] + bf2f(qkvb[oc + 1])) * SCALE_F);
    pk.y = packbf((acc[2] + bf2f(qkvb[oc + 2])) * SCALE_F, (acc[3] + bf2f(qkvb[oc + 3])) * SCALE_F);
    *(uint2*)(sY + tok * 128 + (((2 * mt + (quad >> 1)) ^ m16) << 3) + ((quad & 1) << 2)) = pk;
  }
  __syncthreads();  // barrier 1: K/V/Q visible to all waves

  // ---- S^T = K·Q^T : A = sK rows (j), B = own Q rows ----
  f32x4 S[8];
#pragma unroll
  for (int jt = 0; jt < 8; jt++) { S[jt][0] = 0.f; S[jt][1] = 0.f; S[jt][2] = 0.f; S[jt][3] = 0.f; }
#pragma unroll
  for (int kc = 0; kc < 4; kc++) {
    bf16x8 qf = *(const bf16x8*)(sY + tok * 128 + (((4 * kc + quad) ^ m16) << 3));
#pragma unroll
    for (int jt = 0; jt < 8; jt++) {
      int row = jt * 16 + m16;
      bf16x8 kf = *(const bf16x8*)(sK + row * 128 + (((4 * kc + quad) ^ m16) << 3));
      S[jt] = __builtin_amdgcn_mfma_f32_16x16x32_bf16(kf, qf, S[jt], 0, 0, 0);
    }
  }
  // ---- bias + masks + softmax (lane owns q=tok column; j = jt*16+quad*4+r) ----
  const int ldq = tokc / 25, lhq = (tokc / 5) % 5, lwq = tokc % 5;
  int regQ = 0;
  if (boundary) {
    int gd = wd * 5 + ldq, gh = wh * 5 + lhq, gw = ww * 5 + lwq;
    regQ = (gd < 5 ? 0 : (gd < 8 ? 1 : 2)) * 9 + (gh < 25 ? 0 : (gh < 28 ? 1 : 2)) * 3 +
           (gw < 35 ? 0 : (gw < 38 ? 1 : 2));
  }
  float mx = -1e30f;
#pragma unroll
  for (int jt = 0; jt < 8; jt++) {
#pragma unroll
    for (int r = 0; r < 4; r++) {
      int j = jt * 16 + quad * 4 + r;
      bool jvalid = j < 125;
      int jc = jvalid ? j : 124;
      int ldk = jc / 25, lhk = (jc / 5) % 5, lwk = jc % 5;
      float s = S[jt][r];
      int idx = ((ldq - ldk + 4) * 9 + (lhq - lhk + 4)) * 9 + (lwq - lwk + 4);
      s += bf2f(rpb[idx]);
      if (ldq < ldk) s -= 100.f;
      if (boundary) {
        int gd = wd * 5 + ldk, gh = wh * 5 + lhk, gw = ww * 5 + lwk;
        int regK = (gd < 5 ? 0 : (gd < 8 ? 1 : 2)) * 9 + (gh < 25 ? 0 : (gh < 28 ? 1 : 2)) * 3 +
                   (gw < 35 ? 0 : (gw < 38 ? 1 : 2));
        if (regQ != regK) s -= 100.f;
      }
      if (!jvalid) s = -1e30f;
      S[jt][r] = s;
      mx = fmaxf(mx, s);
    }
  }
  mx = fmaxf(mx, __shfl_xor(mx, 16, 64));
  mx = fmaxf(mx, __shfl_xor(mx, 32, 64));
  float sm = 0.f;
#pragma unroll
  for (int jt = 0; jt < 8; jt++)
#pragma unroll
    for (int r = 0; r < 4; r++) {
      float e = __expf(S[jt][r] - mx);
      S[jt][r] = e;
      sm += e;
    }
  sm += __shfl_xor(sm, 16, 64);
  sm += __shfl_xor(sm, 32, 64);
  float inv = 1.f / sm;
  __syncthreads();  // barrier 2: all waves done reading sK as A
  // P -> sK region (own rows)
#pragma unroll
  for (int jt = 0; jt < 8; jt++) {
    uint2 pk;
    pk.x = packbf(S[jt][0] * inv, S[jt][1] * inv);
    pk.y = packbf(S[jt][2] * inv, S[jt][3] * inv);
    *(uint2*)(sK + tok * 128 + (((2 * jt + (quad >> 1)) ^ m16) << 3) + ((quad & 1) << 2)) = pk;
  }
  // ---- O^T = VT·P : A = sVT rows (c), B = own P rows (no barrier: own-row) ----
  f32x4 O[8];
#pragma unroll
  for (int ct = 0; ct < 8; ct++) { O[ct][0] = 0.f; O[ct][1] = 0.f; O[ct][2] = 0.f; O[ct][3] = 0.f; }
#pragma unroll
  for (int kc = 0; kc < 4; kc++) {
    bf16x8 pf = *(const bf16x8*)(sK + tok * 128 + (((4 * kc + quad) ^ m16) << 3));
#pragma unroll
    for (int ct = 0; ct < 8; ct++) {
      int c = ct * 16 + m16;
      bf16x8 vf = *(const bf16x8*)(sVT + c * 128 + (((4 * kc + quad) ^ m16) << 3));
      O[ct] = __builtin_amdgcn_mfma_f32_16x16x32_bf16(vf, pf, O[ct], 0, 0, 0);
    }
  }
  __syncthreads();  // barrier 3: all waves done reading sVT as A
  // O -> sVT region as sO[tok][c] (own rows)
#pragma unroll
  for (int ct = 0; ct < 8; ct++) {
    uint2 pk;
    pk.x = packbf(O[ct][0], O[ct][1]);
    pk.y = packbf(O[ct][2], O[ct][3]);
    *(uint2*)(sVT + tok * 128 + (((2 * ct + (quad >> 1)) ^ m16) << 3) + ((quad & 1) << 2)) = pk;
  }
  // proj B-frags (own rows)
  bf16x8 biO[4];
#pragma unroll
  for (int kc = 0; kc < 4; kc++)
    biO[kc] = *(const bf16x8*)(sVT + tok * 128 + (((4 * kc + quad) ^ m16) << 3));
  // lane's scatter destination (roll-back)
  size_t xbase;
  {
    int ld = tokc / 25, lh = (tokc / 5) % 5, lw = tokc % 5;
    int d = wd * 5 + ld + shift; if (d >= 10) d -= 10;
    int h = wh * 5 + lh + shift; if (h >= 30) h -= 30;
    int w2 = ww * 5 + lw + shift; if (w2 >= 40) w2 -= 40;
    xbase = ((((size_t)b * 10 + d) * 30 + h) * 40 + w2) * 128;
  }
  // ---- proj^T = WpT·O^T + residual scatter-add ----
#pragma unroll
  for (int mt = 0; mt < 8; mt++) {
    f32x4 acc; acc[0] = 0.f; acc[1] = 0.f; acc[2] = 0.f; acc[3] = 0.f;
#pragma unroll
    for (int kc = 0; kc < 4; kc++) {
      bf16x8 a = *(const bf16x8*)(Wproj + (size_t)(mt * 16 + m16) * 128 + kc * 32 + quad * 8);
      acc = __builtin_amdgcn_mfma_f32_16x16x32_bf16(a, biO[kc], acc, 0, 0, 0);
    }
    if (tok < 125) {
      int oc = mt * 16 + quad * 4;
      u16* xp = X + xbase + oc;
      uint2 old = *(uint2*)xp;
      float f0 = bf2f((u16)(old.x & 0xffff)) + acc[0] + bf2f(projb[oc]);
      float f1 = bf2f((u16)(old.x >> 16)) + acc[1] + bf2f(projb[oc + 1]);
      float f2 = bf2f((u16)(old.y & 0xffff)) + acc[2] + bf2f(projb[oc + 2]);
      float f3 = bf2f((u16)(old.y >> 16)) + acc[3] + bf2f(projb[oc + 3]);
      uint2 nv;
      nv.x = packbf(f0, f1);
      nv.y = packbf(f2, f3);
      *(uint2*)xp = nv;
    }
  }
}

// ---------------- k_mlp v2 (unchanged from R11) ----------------
__global__ __launch_bounds__(512) void k_mlp(u16* __restrict__ X, const u16* __restrict__ W1T,
                                             const u16* __restrict__ b1, const u16* __restrict__ W2T,
                                             const u16* __restrict__ b2, const u16* __restrict__ nw,
                                             const u16* __restrict__ nb) {
  __shared__ u16 sIn[256 * 128];
  __shared__ u16 sW1[64 * 128];
  __shared__ u16 sH[256 * 64];
  __shared__ u16 sW2[128 * 64];
  const int tid = threadIdx.x, lane = tid & 63, wv = tid >> 6;
  const int m16 = lane & 15, quad = lane >> 4;
  const int mbase = blockIdx.x * 256;
  const float nw0 = bf2f(nw[2 * lane]), nb0 = bf2f(nb[2 * lane]);
  const float nw1 = bf2f(nw[2 * lane + 1]), nb1 = bf2f(nb[2 * lane + 1]);
  for (int r = 0; r < 32; r++) {
    int row = wv * 32 + r;
    unsigned int u = *(const unsigned int*)(X + (size_t)(mbase + row) * 128 + 2 * lane);
    float x0 = bf2f((u16)(u & 0xffff)), x1 = bf2f((u16)(u >> 16));
    float mean = wsum(x0 + x1) * (1.f / 128.f);
    float var = wsum(x0 * x0 + x1 * x1) * (1.f / 128.f) - mean * mean;
    float rstd = rsqrtf(var + 1e-5f);
    float y0 = (x0 - mean) * rstd * nw0 + nb0;
    float y1 = (x1 - mean) * rstd * nw1 + nb1;
    *(unsigned int*)(sIn + row * 128 + (((lane >> 2) ^ (row & 15)) << 3) + ((2 * lane) & 7)) =
        packbf(y0, y1);
  }
  f32x4 acc2[8][2];
#pragma unroll
  for (int mt = 0; mt < 8; mt++)
#pragma unroll
    for (int t = 0; t < 2; t++)
#pragma unroll
      for (int r = 0; r < 4; r++) acc2[mt][t][r] = 0.f;
  __syncthreads();
  for (int hc = 0; hc < 8; hc++) {
    for (int idx = tid; idx < 1024; idx += 512) {
      int row = idx >> 4, g = idx & 15;
      uint4 v = *(const uint4*)(W1T + (size_t)(hc * 64 + row) * 128 + g * 8);
      *(uint4*)(sW1 + row * 128 + ((g ^ (row & 15)) << 3)) = v;
    }
    for (int idx = tid; idx < 1024; idx += 512) {
      int row = idx >> 3, g = idx & 7;
      uint4 v = *(const uint4*)(W2T + (size_t)row * 512 + hc * 64 + g * 8);
      *(uint4*)(sW2 + row * 64 + ((g ^ (row & 7)) << 3)) = v;
    }
    __syncthreads();
    f32x4 h4[4][2];
#pragma unroll
    for (int nt = 0; nt < 4; nt++)
#pragma unroll
      for (int t = 0; t < 2; t++)
#pragma unroll
        for (int r = 0; r < 4; r++) h4[nt][t][r] = 0.f;
#pragma unroll
    for (int kc = 0; kc < 4; kc++) {
      bf16x8 bi[2];
#pragma unroll
      for (int t = 0; t < 2; t++) {
        int row = wv * 32 + t * 16 + m16;
        bi[t] = *(const bf16x8*)(sIn + row * 128 + (((4 * kc + quad) ^ m16) << 3));
      }
#pragma unroll
      for (int nt = 0; nt < 4; nt++) {
        int hrow = nt * 16 + m16;
        bf16x8 af = *(const bf16x8*)(sW1 + hrow * 128 + (((4 * kc + quad) ^ m16) << 3));
#pragma unroll
        for (int t = 0; t < 2; t++)
          h4[nt][t] = __builtin_amdgcn_mfma_f32_16x16x32_bf16(af, bi[t], h4[nt][t], 0, 0, 0);
      }
    }
    __syncthreads();
#pragma unroll
    for (int nt = 0; nt < 4; nt++) {
      int hb = nt * 16 + quad * 4;
      float bv0 = bf2f(b1[hc * 64 + hb]);
      float bv1 = bf2f(b1[hc * 64 + hb + 1]);
      float bv2 = bf2f(b1[hc * 64 + hb + 2]);
      float bv3 = bf2f(b1[hc * 64 + hb + 3]);
#pragma unroll
      for (int t = 0; t < 2; t++) {
        int tok = wv * 32 + t * 16 + m16;
        float g0 = gelu_f(h4[nt][t][0] + bv0);
        float g1 = gelu_f(h4[nt][t][1] + bv1);
        float g2 = gelu_f(h4[nt][t][2] + bv2);
        float g3 = gelu_f(h4[nt][t][3] + bv3);
        uint2 pk;
        pk.x = packbf(g0, g1);
        pk.y = packbf(g2, g3);
        int g16 = (2 * nt + (quad >> 1)) ^ (tok & 7);
        *(uint2*)(sH + tok * 64 + (g16 << 3) + ((quad & 1) << 2)) = pk;
      }
    }
    __syncthreads();
#pragma unroll
    for (int kc = 0; kc < 2; kc++) {
      bf16x8 bh[2];
#pragma unroll
      for (int t = 0; t < 2; t++) {
        int tok = wv * 32 + t * 16 + m16;
        bh[t] = *(const bf16x8*)(sH + tok * 64 + ((((4 * kc + quad) ^ (tok & 7))) << 3));
      }
#pragma unroll
      for (int mt = 0; mt < 8; mt++) {
        int oc = mt * 16 + m16;
        bf16x8 af = *(const bf16x8*)(sW2 + oc * 64 + ((((4 * kc + quad) ^ (oc & 7))) << 3));
#pragma unroll
        for (int t = 0; t < 2; t++)
          acc2[mt][t] = __builtin_amdgcn_mfma_f32_16x16x32_bf16(af, bh[t], acc2[mt][t], 0, 0, 0);
      }
    }
    __syncthreads();
  }
#pragma unroll
  for (int mt = 0; mt < 8; mt++) {
    int oc0 = mt * 16 + quad * 4;
    float bv0 = bf2f(b2[oc0]), bv1 = bf2f(b2[oc0 + 1]);
    float bv2 = bf2f(b2[oc0 + 2]), bv3 = bf2f(b2[oc0 + 3]);
#pragma unroll
    for (int t = 0; t < 2; t++) {
      int token = mbase + wv * 32 + t * 16 + m16;
      u16* xp = X + (size_t)token * 128 + oc0;
      uint2 old = *(uint2*)xp;
      float f0 = bf2f((u16)(old.x & 0xffff)) + acc2[mt][t][0] + bv0;
      float f1 = bf2f((u16)(old.x >> 16)) + acc2[mt][t][1] + bv1;
      float f2 = bf2f((u16)(old.y & 0xffff)) + acc2[mt][t][2] + bv2;
      float f3 = bf2f((u16)(old.y >> 16)) + acc2[mt][t][3] + bv3;
      uint2 nv;
      nv.x = packbf(f0, f1);
      nv.y = packbf(f2, f3);
      *(uint2*)xp = nv;
    }
  }
}

// ---------------- final LN + partial pooling ----------------
__global__ __launch_bounds__(256) void k_pool(const u16* __restrict__ X, const u16* __restrict__ vec,
                                              float* __restrict__ pool) {
  __shared__ float sacc[4][128];
  const int tid = threadIdx.x, lane = tid & 63, wv = tid >> 6;
  const int b = blockIdx.x / 10, slice = blockIdx.x % 10;
  const float nw0 = bf2f(vec[VC_NFW + 2 * lane]), nb0 = bf2f(vec[VC_NFB + 2 * lane]);
  const float nw1 = bf2f(vec[VC_NFW + 2 * lane + 1]), nb1 = bf2f(vec[VC_NFB + 2 * lane + 1]);
  float a0 = 0.f, a1 = 0.f;
  for (int t = wv; t < 1200; t += 4) {
    size_t token = (size_t)b * 12000 + slice * 1200 + t;
    unsigned int u = *(const unsigned int*)(X + token * 128 + 2 * lane);
    float x0 = bf2f((u16)(u & 0xffff)), x1 = bf2f((u16)(u >> 16));
    float mean = wsum(x0 + x1) * (1.f / 128.f);
    float var = wsum(x0 * x0 + x1 * x1) * (1.f / 128.f) - mean * mean;
    float rstd = rsqrtf(var + 1e-5f);
    a0 += (x0 - mean) * rstd * nw0 + nb0;
    a1 += (x1 - mean) * rstd * nw1 + nb1;
  }
  sacc[wv][2 * lane] = a0;
  sacc[wv][2 * lane + 1] = a1;
  __syncthreads();
  if (tid < 128) {
    float s = sacc[0][tid] + sacc[1][tid] + sacc[2][tid] + sacc[3][tid];
    atomicAdd(pool + b * 128 + tid, s);
  }
}

// ---------------- head: fp32 output ----------------
__global__ __launch_bounds__(256) void k_head(const float* __restrict__ pool,
                                              const u16* __restrict__ obs,
                                              const u16* __restrict__ vec,
                                              float* __restrict__ out) {
  const int b = blockIdx.x, o = threadIdx.x;
  float acc = bf2f(vec[VC_OBIAS + o]);
  for (int i = 0; i < 128; i++)
    acc += pool[b * 128 + i] * (1.f / 12000.f) * bf2f(vec[VC_OW + i * 256 + o]);
  for (int i = 0; i < 20; i++)
    acc += bf2f(obs[(size_t)b * 132020 + 132000 + i]) * bf2f(vec[VC_OW + (128 + i) * 256 + o]);
  out[b * 256 + o] = acc;
}

extern "C" void kernel_launch(void* const* d_in, const int* in_sizes, int n_in,
                              void* d_out, int out_size, void* d_ws, size_t ws_size,
                              hipStream_t stream) {
  u16* base  = (u16*)d_ws;
  int* flag  = (int*)d_ws;
  float* pool = (float*)((char*)d_ws + 16);
  u16* VEC   = base + 10000;
  u16* WT    = VEC + 45056;
  u16* OBSC  = WT + 393216;
  u16* X     = OBSC + 4224640;   // 49,152,000 — total ~108 MB (no chunk buffers)

  hipMemsetAsync(d_ws, 0, 16 + 32 * 128 * sizeof(float), stream);
  k_scan<<<1, 256, 0, stream>>>((const u16*)d_in[0], flag);
  k_decide<<<1, 64, 0, stream>>>(flag);

  struct CV { int idx; int off; int n; };
  const CV cvs[] = {
      {1, VC_PW, 1408},  {2, VC_PB, 128},   {3, VC_N1W, 256},  {4, VC_N1B, 256},
      {6, VC_QKVB, 768}, {9, VC_PROJB, 256},{10, VC_N2W, 256}, {11, VC_N2B, 256},
      {13, VC_B1, 1024}, {15, VC_B2, 256},  {16, VC_NFW, 128}, {17, VC_NFB, 128},
      {7, VC_RPB, 1458}, {18, VC_OW, 37888},{19, VC_OBIAS, 256}};
  for (const auto& c : cvs)
    k_conv<<<(c.n + 255) / 256, 256, 0, stream>>>(d_in[c.idx], VEC + c.off, c.n, flag);
  k_conv<<<16504, 256, 0, stream>>>(d_in[0], OBSC, 4224640, flag);
  for (int l = 0; l < 2; l++) {
    k_convT2<<<192, 256, 0, stream>>>(d_in[5],  WT + WT_QKV  + l * 49152, 128, 384, l * 49152, flag);
    k_convT2<<<64,  256, 0, stream>>>(d_in[8],  WT + WT_PROJ + l * 16384, 128, 128, l * 16384, flag);
    k_convT2<<<256, 256, 0, stream>>>(d_in[12], WT + WT_W1   + l * 65536, 128, 512, l * 65536, flag);
    k_convT2<<<256, 256, 0, stream>>>(d_in[14], WT + WT_W2   + l * 65536, 512, 128, l * 65536, flag);
  }

  k_patch<<<9600, 256, 0, stream>>>(OBSC, VEC, X);

  for (int l = 0; l < 2; l++) {
    const int shift = l ? 2 : 0;
    k_win<<<3072, 512, 0, stream>>>(X, WT + WT_QKV + l * 49152, WT + WT_PROJ + l * 16384,
                                    VEC + VC_QKVB + l * 384, VEC + VC_PROJB + l * 128,
                                    VEC + VC_N1W + l * 128, VEC + VC_N1B + l * 128,
                                    VEC + VC_RPB + l * 729, shift, l);
    k_mlp<<<1500, 512, 0, stream>>>(X, WT + WT_W1 + l * 65536, VEC + VC_B1 + l * 512,
                                    WT + WT_W2 + l * 65536, VEC + VC_B2 + l * 128,
                                    VEC + VC_N2W + l * 128, VEC + VC_N2B + l * 128);
  }

  k_pool<<<320, 256, 0, stream>>>(X, VEC, pool);
  k_head<<<32, 256, 0, stream>>>(pool, OBSC, VEC, (float*)d_out);
}